// Round 9
// baseline (6670.625 us; speedup 1.0000x reference)
//
#include <hip/hip_runtime.h>
#include <cstdint>
#include <cstddef>

// ---------- types ----------
typedef __attribute__((ext_vector_type(8))) short short8;   // 8 bf16 in 4 VGPRs
typedef __attribute__((ext_vector_type(4))) float f32x4;

#define B_ 64
#define T_ 512
#define I_ 256
#define H_ 1024
#define O_ 256

__device__ __forceinline__ unsigned short f32_to_bf16(float f) {
  unsigned int u = __float_as_uint(f);
  u += 0x7fffu + ((u >> 16) & 1u);           // RNE
  return (unsigned short)(u >> 16);
}
__device__ __forceinline__ float bf16_to_f32(unsigned short h) {
  return __uint_as_float(((unsigned int)h) << 16);
}

__device__ __forceinline__ void gload_lds16(const void* g, void* l) {
  __builtin_amdgcn_global_load_lds((const __attribute__((address_space(1))) void*)g,
                                   (__attribute__((address_space(3))) void*)l, 16, 0, 0);
}

// MALL-write-through stores (bypass L1/L2 -> no cache maintenance ever needed)
__device__ __forceinline__ void store_short_sc(void* p, unsigned short v) {
  unsigned int vv = v;
  asm volatile("global_store_short %0, %1, off sc0 sc1" :: "v"(p), "v"(vv) : "memory");
}
__device__ __forceinline__ void store_int_sc(void* p, int v) {
  asm volatile("global_store_dword %0, %1, off sc0 sc1" :: "v"(p), "v"(v) : "memory");
}
// MALL-coherent 16B load (inline asm: caller MUST s_waitcnt vmcnt before use!)
__device__ __forceinline__ short8 load16_sc(const void* p) {
  short8 r;
  asm volatile("global_load_dwordx4 %0, %1, off sc0 sc1" : "=v"(r) : "v"(p) : "memory");
  return r;
}
// pinned (non-rematerializable) 16B load: executes exactly once (cached path ok)
__device__ __forceinline__ short8 pinned_load16(const void* p) {
  short8 r;
  asm volatile("global_load_dwordx4 %0, %1, off" : "=v"(r) : "v"(p));
  return r;
}

// ---------- conversion kernels ----------
__global__ void cvt_f32_bf16(const float4* __restrict__ s, ushort4* __restrict__ d, int n4) {
  int i = blockIdx.x * blockDim.x + threadIdx.x;
  if (i >= n4) return;
  float4 v = s[i];
  ushort4 o;
  o.x = f32_to_bf16(v.x); o.y = f32_to_bf16(v.y);
  o.z = f32_to_bf16(v.z); o.w = f32_to_bf16(v.w);
  d[i] = o;
}

__global__ void bias_sum(const float* __restrict__ a, const float* __restrict__ b,
                         float* __restrict__ o, int n) {
  int i = blockIdx.x * blockDim.x + threadIdx.x;
  if (i < n) o[i] = a[i] + b[i];
}

// ---------- GEMM: C[M,N] = A[M,K] @ Bm[N,K]^T + bias, 128x128 tile (m97 structure) ----------
template<int OUT_F32>
__global__ __launch_bounds__(256) void gemm_bt(
    const unsigned short* __restrict__ A, const unsigned short* __restrict__ Bm,
    const float* __restrict__ bias, void* __restrict__ Cout, int N_, int K_)
{
  __shared__ unsigned short As[128*32];
  __shared__ unsigned short Bs[128*32];
  const int tid = threadIdx.x;
  const int l = tid & 63, w = tid >> 6;
  const int row0 = blockIdx.y * 128, col0 = blockIdx.x * 128;
  const int wr = w >> 1, wc = w & 1;          // 2x2 waves, each 64x64
  const int lrow = l & 15, lk8 = (l >> 4) * 8;

  f32x4 acc[4][4] = {};

  const int nkb = K_ >> 5;
  for (int kb = 0; kb < nkb; ++kb) {
    #pragma unroll
    for (int c = 0; c < 2; ++c) {
      const int off = w*2048 + c*1024 + l*16;   // byte offset within 8KB tile
      const int row = off >> 6, colb = off & 63;
      gload_lds16((const char*)A  + ((size_t)(row0+row)*K_ + kb*32)*2 + colb,
                  (char*)As + w*2048 + c*1024);
      gload_lds16((const char*)Bm + ((size_t)(col0+row)*K_ + kb*32)*2 + colb,
                  (char*)Bs + w*2048 + c*1024);
    }
    __syncthreads();
    short8 af[4], bfr[4];
    #pragma unroll
    for (int m=0;m<4;++m) af[m]  = *(const short8*)&As[(wr*64 + m*16 + lrow)*32 + lk8];
    #pragma unroll
    for (int n=0;n<4;++n) bfr[n] = *(const short8*)&Bs[(wc*64 + n*16 + lrow)*32 + lk8];
    #pragma unroll
    for (int m=0;m<4;++m)
      #pragma unroll
      for (int n=0;n<4;++n)
        acc[m][n] = __builtin_amdgcn_mfma_f32_16x16x32_bf16(af[m], bfr[n], acc[m][n], 0,0,0);
    __syncthreads();
  }

  #pragma unroll
  for (int n=0;n<4;++n) {
    const int col = col0 + wc*64 + n*16 + lrow;
    const float bv = bias[col];
    #pragma unroll
    for (int m=0;m<4;++m) {
      const int rowb = row0 + wr*64 + m*16 + (l>>4)*4;
      #pragma unroll
      for (int r=0;r<4;++r) {
        const float v = acc[m][n][r] + bv;
        if (OUT_F32) ((float*)Cout)[(size_t)(rowb+r)*N_ + col] = v;
        else ((unsigned short*)Cout)[(size_t)(rowb+r)*N_ + col] = f32_to_bf16(v);
      }
    }
  }
}

// ---------- RNN scan ----------
// 128 wgs x 512 threads: sg = wg&15 (4 samples), rgO = wg>>4 (128 cols via 8
// waves x 16 cols). Whh rows pinned in AGPR/VGPR for all 512 steps.
// Sync: PER-WAVE release flags (64 per group) — each wave publishes after its
// own vmcnt(0) drain (no intra-wg pre-sync, no tid0 hop); consumers poll all
// 64 flags with one coalesced lane-per-flag load + __all. LDS staging is
// double-buffered (read t&1, write (t+1)&1) so only ONE __syncthreads/step.
// MODE 0: h buffer is H1[B*T][H]. MODE 1: ping-pong [2][B][H], final in slot 1.
#define SCAN_STEP(tcur, XREG)                                                        \
  {                                                                                  \
    const int t = (tcur);                                                            \
    f32x4 acc0 = {}, acc1 = {}, acc2 = {}, acc3 = {};                                \
    if (t > 0) {                                                                     \
      const unsigned short* lb = &lds_h[t & 1][arow][0];                             \
      _Pragma("unroll")                                                              \
      for (int kk = 0; kk < 32; kk += 4) {                                           \
        short8 a0 = *(const short8*)&lb[(kk+0)*32 + lk8];                            \
        short8 a1 = *(const short8*)&lb[(kk+1)*32 + lk8];                            \
        short8 a2 = *(const short8*)&lb[(kk+2)*32 + lk8];                            \
        short8 a3 = *(const short8*)&lb[(kk+3)*32 + lk8];                            \
        acc0 = __builtin_amdgcn_mfma_f32_16x16x32_bf16(a0, breg[kk+0], acc0, 0,0,0); \
        acc1 = __builtin_amdgcn_mfma_f32_16x16x32_bf16(a1, breg[kk+1], acc1, 0,0,0); \
        acc2 = __builtin_amdgcn_mfma_f32_16x16x32_bf16(a2, breg[kk+2], acc2, 0,0,0); \
        acc3 = __builtin_amdgcn_mfma_f32_16x16x32_bf16(a3, breg[kk+3], acc3, 0,0,0); \
      }                                                                              \
    }                                                                                \
    if (l < 16) {                                                                    \
      _Pragma("unroll")                                                              \
      for (int r = 0; r < 4; ++r) {                                                  \
        const int s = sg*4 + r;                                                      \
        float v = acc0[r] + acc1[r] + acc2[r] + acc3[r]                              \
                + bf16_to_f32((unsigned short)XREG[r]);                              \
        v = fmaxf(v, 0.f);                                                           \
        const unsigned short hv = f32_to_bf16(v);                                    \
        unsigned short* dst = (MODE==0)                                              \
          ? hbuf + ((size_t)s*T_ + t)*H_ + col                                       \
          : hbuf + ((size_t)((t&1)*B_ + s))*H_ + col;                                \
        store_short_sc(dst, hv);                                                     \
      }                                                                              \
    }                                                                                \
    if (t < T_-1) {                                                                  \
      asm volatile("s_waitcnt vmcnt(0)" ::: "memory");  /* THIS wave's stores @MALL */\
      if (l == 0) store_int_sc(&flags[rgO*8 + w], t+1); /* per-wave publish */       \
      { int fv;                                                                      \
        do { fv = __hip_atomic_load(flags + l, __ATOMIC_RELAXED,                     \
                                    __HIP_MEMORY_SCOPE_AGENT);                       \
        } while (!__all(fv >= t+1)); }                   /* all 64 producer waves */ \
      const unsigned short* hrow = (MODE==0)                                         \
        ? hbuf + ((size_t)(sg*4 + (w>>1))*T_ + t)*H_                                 \
        : hbuf + ((size_t)((t&1)*B_ + sg*4 + (w>>1)))*H_;                            \
      const int tn = (t+2 < T_) ? (t+2) : (T_-1);                                    \
      const unsigned short* xpp = xp + ((size_t)(sg*4)*T_ + tn)*H_ + col;            \
      short8 sv = load16_sc(hrow + (w&1)*512 + l*8);     /* 1 outstanding */         \
      _Pragma("unroll")                                                              \
      for (int r = 0; r < 4; ++r)                        /* +4 outstanding */        \
        asm volatile("global_load_ushort %0, %1, off"                               \
                     : "=v"(XREG[r]) : "v"(xpp + (size_t)r*T_*H_) : "memory");       \
      asm volatile("s_waitcnt vmcnt(4)" ::: "memory");   /* wait stage load only */  \
      *(short8*)&lds_h[(t+1) & 1][w>>1][(w&1)*512 + l*8] = sv;                       \
      __syncthreads();                                   /* LDS visible for t+1 */   \
    }                                                                                \
  }

template<int MODE>
__global__ __launch_bounds__(512, 2) void rnn_scan(
    const unsigned short* __restrict__ whh,
    const unsigned short* __restrict__ xp,
    unsigned short* __restrict__ hbuf,
    int* __restrict__ bar)
{
  // double-buffered; +16 pad/row: stride 2080B -> 8-bank shift/row -> max 2-way (free)
  __shared__ unsigned short lds_h[2][4][1040];

  const int wg = blockIdx.x;          // 0..127
  const int sg = wg & 15;             // sample-group (4 samples)
  const int rgO = wg >> 4;            // 0..7 col-group (128 cols)
  const int tid = threadIdx.x;        // 0..511
  const int l = tid & 63;
  const int w = tid >> 6;             // 0..7
  const int lrow = l & 15;
  const int lk8 = (l >> 4) * 8;
  const int col = rgO*128 + w*16 + lrow;   // hidden index this lane produces
  const int arow = lrow & 3;               // LDS A-row (4 samples dup to 16)
  int* flags = bar + sg*64;                // 64 per-wave flags per group (256B)

  // Whh rows pinned in registers: breg[kk] = Whh[col][kk*32 + lk8 .. +7]
  short8 breg[32];
  #pragma unroll
  for (int kk=0; kk<32; ++kk)
    breg[kk] = pinned_load16(&whh[(size_t)col*H_ + kk*32 + lk8]);

  // xp pipeline: xa = xp[even t], xb = xp[odd t]; reloaded 2 steps ahead.
  unsigned int xa[4], xb[4];
  #pragma unroll
  for (int r=0; r<4; ++r) {
    asm volatile("global_load_ushort %0, %1, off" : "=v"(xa[r])
      : "v"(xp + ((size_t)(sg*4+r)*T_ + 0)*H_ + col) : "memory");
    asm volatile("global_load_ushort %0, %1, off" : "=v"(xb[r])
      : "v"(xp + ((size_t)(sg*4+r)*T_ + 1)*H_ + col) : "memory");
  }
  asm volatile("s_waitcnt vmcnt(0)" ::: "memory");
  __builtin_amdgcn_sched_barrier(0);

  for (int t2 = 0; t2 < T_; t2 += 2) {
    SCAN_STEP(t2,   xa);   // reloads xa = xp[t2+2]
    SCAN_STEP(t2+1, xb);   // reloads xb = xp[t2+3]
  }
}

// ---------- final FC: out[64,256] = h2 @ fcW^T + fcb (f32 out) ----------
__global__ __launch_bounds__(64) void fc_kernel(const unsigned short* __restrict__ h,
                                                const unsigned short* __restrict__ fw,
                                                const float* __restrict__ fb,
                                                float* __restrict__ out) {
  const int l = threadIdx.x;
  const int bx = blockIdx.x, by = blockIdx.y;   // bx: 16 col tiles, by: 4 row tiles
  const int lrow = l & 15, lk8 = (l>>4)*8;
  f32x4 acc = {};
  #pragma unroll
  for (int kk=0; kk<32; ++kk) {
    short8 a = *(const short8*)&h [(size_t)(by*16 + lrow)*H_ + kk*32 + lk8];
    short8 b = *(const short8*)&fw[(size_t)(bx*16 + lrow)*H_ + kk*32 + lk8];
    acc = __builtin_amdgcn_mfma_f32_16x16x32_bf16(a, b, acc, 0,0,0);
  }
  const int col = bx*16 + lrow;
  const float bv = fb[col];
  #pragma unroll
  for (int r=0;r<4;++r) {
    const int row = by*16 + (l>>4)*4 + r;
    out[row*O_ + col] = acc[r] + bv;
  }
}

// ---------- launch ----------
extern "C" void kernel_launch(void* const* d_in, const int* in_sizes, int n_in,
                              void* d_out, int out_size, void* d_ws, size_t ws_size,
                              hipStream_t stream) {
  const float* x    = (const float*)d_in[0];
  const float* wih0 = (const float*)d_in[1];
  const float* bih0 = (const float*)d_in[2];
  const float* whh0 = (const float*)d_in[3];
  const float* bhh0 = (const float*)d_in[4];
  const float* wih1 = (const float*)d_in[5];
  const float* bih1 = (const float*)d_in[6];
  const float* whh1 = (const float*)d_in[7];
  const float* bhh1 = (const float*)d_in[8];
  const float* fcw  = (const float*)d_in[9];
  const float* fcb  = (const float*)d_in[10];

  char* ws = (char*)d_ws;
  // workspace layout (bytes). total ~151.3 MiB
  unsigned short* XBF  = (unsigned short*)(ws + 0);          // 16,777,216  x bf16
  unsigned short* WIH0 = (unsigned short*)(ws + 16777216);   //    524,288
  unsigned short* WHH0 = (unsigned short*)(ws + 17301504);   //  2,097,152
  unsigned short* WIH1 = (unsigned short*)(ws + 19398656);   //  2,097,152
  unsigned short* WHH1 = (unsigned short*)(ws + 21495808);   //  2,097,152
  unsigned short* FCW  = (unsigned short*)(ws + 23592960);   //    524,288
  float*          BIAS0= (float*)(ws + 24117248);            //      4,096
  float*          BIAS1= (float*)(ws + 24121344);            //      4,096
  unsigned short* XP   = (unsigned short*)(ws + 24125440);   // 67,108,864  (xp0 then xp1)
  unsigned short* H1   = (unsigned short*)(ws + 91234304);   // 67,108,864
  unsigned short* H2   = (unsigned short*)(ws + 158343168);  //    262,144  ping-pong
  int*            BAR  = (int*)(ws + 158605312);             //      8,192  flag lines

  // flag lines must be zero each call (harness poisons ws once with 0xAA)
  hipMemsetAsync(BAR, 0, 8192, stream);

  // fp32 -> bf16 conversions
  cvt_f32_bf16<<<dim3(8192), 256, 0, stream>>>((const float4*)x,    (ushort4*)XBF,  2097152);
  cvt_f32_bf16<<<dim3(256),  256, 0, stream>>>((const float4*)wih0, (ushort4*)WIH0, 65536);
  cvt_f32_bf16<<<dim3(1024), 256, 0, stream>>>((const float4*)whh0, (ushort4*)WHH0, 262144);
  cvt_f32_bf16<<<dim3(1024), 256, 0, stream>>>((const float4*)wih1, (ushort4*)WIH1, 262144);
  cvt_f32_bf16<<<dim3(1024), 256, 0, stream>>>((const float4*)whh1, (ushort4*)WHH1, 262144);
  cvt_f32_bf16<<<dim3(256),  256, 0, stream>>>((const float4*)fcw,  (ushort4*)FCW,  65536);
  bias_sum<<<dim3(4), 256, 0, stream>>>(bih0, bhh0, BIAS0, H_);
  bias_sum<<<dim3(4), 256, 0, stream>>>(bih1, bhh1, BIAS1, H_);

  // xp0 = x @ Wih0^T + (bih0+bhh0)   [M=32768, N=1024, K=256]
  gemm_bt<0><<<dim3(8, 256), 256, 0, stream>>>(XBF, WIH0, BIAS0, XP, H_, I_);
  // scan layer 0 -> H1[B*T][H]
  rnn_scan<0><<<dim3(128), 512, 0, stream>>>(WHH0, XP, H1, BAR);
  // xp1 = H1 @ Wih1^T + (bih1+bhh1)  [M=32768, N=1024, K=1024]
  gemm_bt<0><<<dim3(8, 256), 256, 0, stream>>>(H1, WIH1, BIAS1, XP, H_, H_);
  // scan layer 1 -> ping-pong, final state in slot 1
  rnn_scan<1><<<dim3(128), 512, 0, stream>>>(WHH1, XP, H2, BAR + 2048);
  // out = h2_last @ fcW^T + fcb
  fc_kernel<<<dim3(16, 4), 64, 0, stream>>>(H2 + (size_t)B_*H_, FCW, fcb, (float*)d_out);
}

// Round 11
// 3006.568 us; speedup vs baseline: 2.2187x; 2.2187x over previous
//
#include <hip/hip_runtime.h>
#include <cstdint>
#include <cstddef>

// ---------- types ----------
typedef __attribute__((ext_vector_type(8))) short short8;   // 8 bf16 in 4 VGPRs
typedef __attribute__((ext_vector_type(4))) float f32x4;

#define B_ 64
#define T_ 512
#define I_ 256
#define H_ 1024
#define O_ 256

__device__ __forceinline__ unsigned short f32_to_bf16(float f) {
  unsigned int u = __float_as_uint(f);
  u += 0x7fffu + ((u >> 16) & 1u);           // RNE
  return (unsigned short)(u >> 16);
}
__device__ __forceinline__ float bf16_to_f32(unsigned short h) {
  return __uint_as_float(((unsigned int)h) << 16);
}

__device__ __forceinline__ void gload_lds16(const void* g, void* l) {
  __builtin_amdgcn_global_load_lds((const __attribute__((address_space(1))) void*)g,
                                   (__attribute__((address_space(3))) void*)l, 16, 0, 0);
}

// MALL-write-through stores (bypass L1/L2 -> no cache maintenance ever needed)
__device__ __forceinline__ void store_short_sc(void* p, unsigned short v) {
  unsigned int vv = v;
  asm volatile("global_store_short %0, %1, off sc0 sc1" :: "v"(p), "v"(vv) : "memory");
}
__device__ __forceinline__ void store_int_sc(void* p, int v) {
  asm volatile("global_store_dword %0, %1, off sc0 sc1" :: "v"(p), "v"(v) : "memory");
}
// MALL-coherent 16B load (inline asm: caller MUST s_waitcnt vmcnt before use!)
__device__ __forceinline__ short8 load16_sc(const void* p) {
  short8 r;
  asm volatile("global_load_dwordx4 %0, %1, off sc0 sc1" : "=v"(r) : "v"(p) : "memory");
  return r;
}
// pinned (non-rematerializable) 16B load: executes exactly once (cached path ok)
__device__ __forceinline__ short8 pinned_load16(const void* p) {
  short8 r;
  asm volatile("global_load_dwordx4 %0, %1, off" : "=v"(r) : "v"(p));
  return r;
}

// ---------- conversion kernels ----------
__global__ void cvt_f32_bf16(const float4* __restrict__ s, ushort4* __restrict__ d, int n4) {
  int i = blockIdx.x * blockDim.x + threadIdx.x;
  if (i >= n4) return;
  float4 v = s[i];
  ushort4 o;
  o.x = f32_to_bf16(v.x); o.y = f32_to_bf16(v.y);
  o.z = f32_to_bf16(v.z); o.w = f32_to_bf16(v.w);
  d[i] = o;
}

__global__ void bias_sum(const float* __restrict__ a, const float* __restrict__ b,
                         float* __restrict__ o, int n) {
  int i = blockIdx.x * blockDim.x + threadIdx.x;
  if (i < n) o[i] = a[i] + b[i];
}

// ---------- GEMM: C[M,N] = A[M,K] @ Bm[N,K]^T + bias, 128x128 tile (m97 structure) ----------
template<int OUT_F32>
__global__ __launch_bounds__(256) void gemm_bt(
    const unsigned short* __restrict__ A, const unsigned short* __restrict__ Bm,
    const float* __restrict__ bias, void* __restrict__ Cout, int N_, int K_)
{
  __shared__ unsigned short As[128*32];
  __shared__ unsigned short Bs[128*32];
  const int tid = threadIdx.x;
  const int l = tid & 63, w = tid >> 6;
  const int row0 = blockIdx.y * 128, col0 = blockIdx.x * 128;
  const int wr = w >> 1, wc = w & 1;          // 2x2 waves, each 64x64
  const int lrow = l & 15, lk8 = (l >> 4) * 8;

  f32x4 acc[4][4] = {};

  const int nkb = K_ >> 5;
  for (int kb = 0; kb < nkb; ++kb) {
    #pragma unroll
    for (int c = 0; c < 2; ++c) {
      const int off = w*2048 + c*1024 + l*16;   // byte offset within 8KB tile
      const int row = off >> 6, colb = off & 63;
      gload_lds16((const char*)A  + ((size_t)(row0+row)*K_ + kb*32)*2 + colb,
                  (char*)As + w*2048 + c*1024);
      gload_lds16((const char*)Bm + ((size_t)(col0+row)*K_ + kb*32)*2 + colb,
                  (char*)Bs + w*2048 + c*1024);
    }
    __syncthreads();
    short8 af[4], bfr[4];
    #pragma unroll
    for (int m=0;m<4;++m) af[m]  = *(const short8*)&As[(wr*64 + m*16 + lrow)*32 + lk8];
    #pragma unroll
    for (int n=0;n<4;++n) bfr[n] = *(const short8*)&Bs[(wc*64 + n*16 + lrow)*32 + lk8];
    #pragma unroll
    for (int m=0;m<4;++m)
      #pragma unroll
      for (int n=0;n<4;++n)
        acc[m][n] = __builtin_amdgcn_mfma_f32_16x16x32_bf16(af[m], bfr[n], acc[m][n], 0,0,0);
    __syncthreads();
  }

  #pragma unroll
  for (int n=0;n<4;++n) {
    const int col = col0 + wc*64 + n*16 + lrow;
    const float bv = bias[col];
    #pragma unroll
    for (int m=0;m<4;++m) {
      const int rowb = row0 + wr*64 + m*16 + (l>>4)*4;
      #pragma unroll
      for (int r=0;r<4;++r) {
        const float v = acc[m][n][r] + bv;
        if (OUT_F32) ((float*)Cout)[(size_t)(rowb+r)*N_ + col] = v;
        else ((unsigned short*)Cout)[(size_t)(rowb+r)*N_ + col] = f32_to_bf16(v);
      }
    }
  }
}

// ---------- fused 2-layer RNN, wave-role split (wg-uniform) ----------
// 128 wgs x 512 threads, launch_bounds(512,2) — EXACTLY r5's proven launch
// config (1 wg/CU on 128 CUs; 2 waves/SIMD => <=256 regs/wave enforced).
// sg = wg&7 (8 samples), colg = wg>>3 (0..15, 64 cols). Waves 0-3: LAYER 0,
// pin Whh0 rows (128 regs, the proven max). Waves 4-7: LAYER 1, pin Whh1
// (128 regs) + STREAM Wih1 via cached loads (L2-resident).
// Superstep t (0..512):
//   L0 (t<512):  h1_t     = relu(xp0_t + h1_{t-1}@Whh0^T)            -> h1pp[t&1]
//   L1 (t>=1):   h2_{t-1} = relu(h1_{t-1}@Wih1^T + b1 + h2_{t-2}@Whh1^T) -> h2pp[(t-1)&1]
// Both read the SAME lds_h1 (h1_{t-1}); L1 additionally lds_h2 (h2_{t-2}).
// ONE flag set, wg-uniform publish+poll (r5's exact sync skeleton):
//   vmcnt(0) -> syncthreads -> tid0 publish flags[colg]=t+1 -> poll 16 flags
//   -> stage h1_t + h2_{t-1} (4x16B sc loads/lane) -> lds -> syncthreads.
#define SUPERSTEP(tcur, XREG)                                                         \
  {                                                                                   \
    const int t = (tcur);                                                             \
    if (w < 4) {                                                                      \
      f32x4 ac0 = {}, ac1 = {}, ac2 = {}, ac3 = {};                                   \
      if (t > 0 && t < T_) {                                                          \
        _Pragma("unroll")                                                             \
        for (int kk = 0; kk < 32; kk += 4) {                                          \
          short8 a0 = *(const short8*)&lds_h1[arow][(kk+0)*32 + lk8];                 \
          short8 a1 = *(const short8*)&lds_h1[arow][(kk+1)*32 + lk8];                 \
          short8 a2 = *(const short8*)&lds_h1[arow][(kk+2)*32 + lk8];                 \
          short8 a3 = *(const short8*)&lds_h1[arow][(kk+3)*32 + lk8];                 \
          ac0 = __builtin_amdgcn_mfma_f32_16x16x32_bf16(a0, breg[kk+0], ac0, 0,0,0);  \
          ac1 = __builtin_amdgcn_mfma_f32_16x16x32_bf16(a1, breg[kk+1], ac1, 0,0,0);  \
          ac2 = __builtin_amdgcn_mfma_f32_16x16x32_bf16(a2, breg[kk+2], ac2, 0,0,0);  \
          ac3 = __builtin_amdgcn_mfma_f32_16x16x32_bf16(a3, breg[kk+3], ac3, 0,0,0);  \
        }                                                                             \
      }                                                                               \
      if (t < T_ && l < 32) {                                                         \
        _Pragma("unroll")                                                             \
        for (int r = 0; r < 4; ++r) {                                                 \
          const int smp = sg*8 + (l>>4)*4 + r;                                        \
          float v = ac0[r] + ac1[r] + ac2[r] + ac3[r]                                 \
                  + bf16_to_f32((unsigned short)XREG[r]);                             \
          v = fmaxf(v, 0.f);                                                          \
          store_short_sc(h1pp + ((size_t)((t&1)*B_ + smp))*H_ + col, f32_to_bf16(v)); \
        }                                                                             \
      }                                                                               \
    } else {                                                                          \
      f32x4 aI0 = {}, aI1 = {}, aH0 = {}, aH1 = {};                                   \
      if (t >= 1) {                                                                   \
        _Pragma("unroll")                                                             \
        for (int kk = 0; kk < 32; kk += 2) {                                          \
          short8 a0 = *(const short8*)&lds_h1[arow][(kk+0)*32 + lk8];                 \
          short8 a1 = *(const short8*)&lds_h1[arow][(kk+1)*32 + lk8];                 \
          short8 w0 = *(const short8*)&wih1[(size_t)col*H_ + (kk+0)*32 + lk8];        \
          short8 w1 = *(const short8*)&wih1[(size_t)col*H_ + (kk+1)*32 + lk8];        \
          aI0 = __builtin_amdgcn_mfma_f32_16x16x32_bf16(a0, w0, aI0, 0,0,0);          \
          aI1 = __builtin_amdgcn_mfma_f32_16x16x32_bf16(a1, w1, aI1, 0,0,0);          \
        }                                                                             \
        if (t >= 2) {                                                                 \
          _Pragma("unroll")                                                           \
          for (int kk = 0; kk < 32; kk += 2) {                                        \
            short8 a0 = *(const short8*)&lds_h2[arow][(kk+0)*32 + lk8];               \
            short8 a1 = *(const short8*)&lds_h2[arow][(kk+1)*32 + lk8];               \
            aH0 = __builtin_amdgcn_mfma_f32_16x16x32_bf16(a0, breg[kk+0], aH0, 0,0,0);\
            aH1 = __builtin_amdgcn_mfma_f32_16x16x32_bf16(a1, breg[kk+1], aH1, 0,0,0);\
          }                                                                           \
        }                                                                             \
        if (l < 32) {                                                                 \
          _Pragma("unroll")                                                           \
          for (int r = 0; r < 4; ++r) {                                               \
            const int smp = sg*8 + (l>>4)*4 + r;                                      \
            float v = aI0[r] + aI1[r] + aH0[r] + aH1[r] + b1v;                        \
            v = fmaxf(v, 0.f);                                                        \
            store_short_sc(h2pp + ((size_t)(((t-1)&1)*B_ + smp))*H_ + col,            \
                           f32_to_bf16(v));                                           \
          }                                                                           \
        }                                                                             \
      }                                                                               \
    }                                                                                 \
    if (t < T_) {                                                                     \
      asm volatile("s_waitcnt vmcnt(0)" ::: "memory");   /* this wave's stores @MALL*/\
      __syncthreads();                                   /* all 8 waves drained */    \
      if (tid == 0) store_int_sc(&flags[colg], t+1);     /* one publish per wg */     \
      { int fv;                                                                       \
        do { fv = __hip_atomic_load(flags + (l & 15), __ATOMIC_RELAXED,               \
                                    __HIP_MEMORY_SCOPE_AGENT);                        \
        } while (!__all(fv >= t+1)); }                   /* all 16 colg wgs of sg */  \
      const int r0 = (w & 3) * 2;                                                     \
      const unsigned short* srcb = (w < 4)                                            \
        ? h1pp + ((size_t)((t&1)*B_ + sg*8))*H_                                       \
        : h2pp + ((size_t)(((t-1)&1)*B_ + sg*8))*H_;                                  \
      short8 sv0 = load16_sc(srcb + (size_t)(r0+0)*H_ + 0   + l*8);                   \
      short8 sv1 = load16_sc(srcb + (size_t)(r0+0)*H_ + 512 + l*8);                   \
      short8 sv2 = load16_sc(srcb + (size_t)(r0+1)*H_ + 0   + l*8);                   \
      short8 sv3 = load16_sc(srcb + (size_t)(r0+1)*H_ + 512 + l*8);                   \
      if (w < 4) {                                                                    \
        const int tn = (t+2 < T_) ? (t+2) : (T_-1);                                   \
        _Pragma("unroll")                                                             \
        for (int r = 0; r < 4; ++r)                                                   \
          asm volatile("global_load_ushort %0, %1, off" : "=v"(XREG[r])               \
            : "v"(xp + ((size_t)(sg*8 + (l>>4)*4 + r)*T_ + tn)*H_ + col) : "memory"); \
        asm volatile("s_waitcnt vmcnt(4)" ::: "memory"); /* 4 sc done, xp pending */  \
        *(short8*)&lds_h1[r0+0][0   + l*8] = sv0;                                     \
        *(short8*)&lds_h1[r0+0][512 + l*8] = sv1;                                     \
        *(short8*)&lds_h1[r0+1][0   + l*8] = sv2;                                     \
        *(short8*)&lds_h1[r0+1][512 + l*8] = sv3;                                     \
      } else {                                                                        \
        asm volatile("s_waitcnt vmcnt(0)" ::: "memory");                              \
        *(short8*)&lds_h2[r0+0][0   + l*8] = sv0;                                     \
        *(short8*)&lds_h2[r0+0][512 + l*8] = sv1;                                     \
        *(short8*)&lds_h2[r0+1][0   + l*8] = sv2;                                     \
        *(short8*)&lds_h2[r0+1][512 + l*8] = sv3;                                     \
      }                                                                               \
      __syncthreads();                                   /* LDS visible for t+1 */    \
    }                                                                                 \
  }

__global__ __launch_bounds__(512, 2) void rnn_fused(
    const unsigned short* __restrict__ whh0,
    const unsigned short* __restrict__ wih1,
    const unsigned short* __restrict__ whh1,
    const unsigned short* __restrict__ xp,     // xp0 = x@Wih0^T + b  [B][T][H]
    const float* __restrict__ bias1,           // bih1 + bhh1
    unsigned short* __restrict__ h1pp,         // [2][B][H] ping-pong
    unsigned short* __restrict__ h2pp,         // [2][B][H]; final h2 in slot 1
    int* __restrict__ bar)
{
  // +16 pad/row: stride 2080B -> 8-bank shift/row -> max 2-way (free). 33KB total
  __shared__ unsigned short lds_h1[8][1040];
  __shared__ unsigned short lds_h2[8][1040];

  const int wg = blockIdx.x;            // 0..127
  const int sg = wg & 7;                // sample-group (8 samples)
  const int colg = wg >> 3;             // 0..15 col-group (64 cols)
  const int tid = threadIdx.x;          // 0..511
  const int l = tid & 63;
  const int w = tid >> 6;               // 0..7 (0-3: L0, 4-7: L1)
  const int lrow = l & 15;
  const int lk8 = (l >> 4) * 8;
  const int col = colg*64 + (w & 3)*16 + lrow;  // hidden index this lane produces
  const int arow = lrow & 7;                    // LDS A-row (8 samples dup to 16)
  int* flags = bar + sg*64;                     // 16 flags/group, 256B-spaced

  // pinned recurrent weights (128 regs/wave — the proven envelope):
  // L0 waves: Whh0 rows; L1 waves: Whh1 rows. Wih1 is streamed, never pinned.
  const unsigned short* wbase = (w < 4) ? whh0 : whh1;
  short8 breg[32];
  #pragma unroll
  for (int kk=0; kk<32; ++kk)
    breg[kk] = pinned_load16(&wbase[(size_t)col*H_ + kk*32 + lk8]);
  asm volatile("s_waitcnt vmcnt(0)" ::: "memory");
  __builtin_amdgcn_sched_barrier(0);

  const float b1v = bias1[col];

  // xp pipeline (L0 waves only): xa = xp[even t], xb = xp[odd t]; 2-ahead reload.
  unsigned int xa[4], xb[4];
  if (w < 4) {
    #pragma unroll
    for (int r=0; r<4; ++r) {
      asm volatile("global_load_ushort %0, %1, off" : "=v"(xa[r])
        : "v"(xp + ((size_t)(sg*8 + (l>>4)*4 + r)*T_ + 0)*H_ + col) : "memory");
      asm volatile("global_load_ushort %0, %1, off" : "=v"(xb[r])
        : "v"(xp + ((size_t)(sg*8 + (l>>4)*4 + r)*T_ + 1)*H_ + col) : "memory");
    }
    asm volatile("s_waitcnt vmcnt(0)" ::: "memory");
  }
  __builtin_amdgcn_sched_barrier(0);

  for (int t2 = 0; t2 < T_; t2 += 2) {
    SUPERSTEP(t2,   xa);
    SUPERSTEP(t2+1, xb);
  }
  SUPERSTEP(T_, xa);   // t=512: L1 tail only (h2_511 -> h2pp slot 1); no barrier
}

// ---------- final FC: out[64,256] = h2 @ fcW^T + fcb (f32 out) ----------
__global__ __launch_bounds__(64) void fc_kernel(const unsigned short* __restrict__ h,
                                                const unsigned short* __restrict__ fw,
                                                const float* __restrict__ fb,
                                                float* __restrict__ out) {
  const int l = threadIdx.x;
  const int bx = blockIdx.x, by = blockIdx.y;   // bx: 16 col tiles, by: 4 row tiles
  const int lrow = l & 15, lk8 = (l>>4)*8;
  f32x4 acc = {};
  #pragma unroll
  for (int kk=0; kk<32; ++kk) {
    short8 a = *(const short8*)&h [(size_t)(by*16 + lrow)*H_ + kk*32 + lk8];
    short8 b = *(const short8*)&fw[(size_t)(bx*16 + lrow)*H_ + kk*32 + lk8];
    acc = __builtin_amdgcn_mfma_f32_16x16x32_bf16(a, b, acc, 0,0,0);
  }
  const int col = bx*16 + lrow;
  const float bv = fb[col];
  #pragma unroll
  for (int r=0;r<4;++r) {
    const int row = by*16 + (l>>4)*4 + r;
    out[row*O_ + col] = acc[r] + bv;
  }
}

// ---------- launch ----------
extern "C" void kernel_launch(void* const* d_in, const int* in_sizes, int n_in,
                              void* d_out, int out_size, void* d_ws, size_t ws_size,
                              hipStream_t stream) {
  const float* x    = (const float*)d_in[0];
  const float* wih0 = (const float*)d_in[1];
  const float* bih0 = (const float*)d_in[2];
  const float* whh0 = (const float*)d_in[3];
  const float* bhh0 = (const float*)d_in[4];
  const float* wih1 = (const float*)d_in[5];
  const float* bih1 = (const float*)d_in[6];
  const float* whh1 = (const float*)d_in[7];
  const float* bhh1 = (const float*)d_in[8];
  const float* fcw  = (const float*)d_in[9];
  const float* fcb  = (const float*)d_in[10];

  char* ws = (char*)d_ws;
  // workspace layout (bytes)
  unsigned short* XBF  = (unsigned short*)(ws + 0);          // 16,777,216  x bf16
  unsigned short* WIH0 = (unsigned short*)(ws + 16777216);   //    524,288
  unsigned short* WHH0 = (unsigned short*)(ws + 17301504);   //  2,097,152
  unsigned short* WIH1 = (unsigned short*)(ws + 19398656);   //  2,097,152
  unsigned short* WHH1 = (unsigned short*)(ws + 21495808);   //  2,097,152
  unsigned short* FCW  = (unsigned short*)(ws + 23592960);   //    524,288
  float*          BIAS0= (float*)(ws + 24117248);            //      4,096
  float*          BIAS1= (float*)(ws + 24121344);            //      4,096
  unsigned short* XP   = (unsigned short*)(ws + 24125440);   // 67,108,864  xp0 [B][T][H]
  unsigned short* H1PP = (unsigned short*)(ws + 91234304);   //    262,144  h1 ping-pong
  unsigned short* H2PP = (unsigned short*)(ws + 158343168);  //    262,144  h2 ping-pong
  int*            BAR  = (int*)(ws + 158605312);             //      8,192  flag lines

  // ALL flags live in [BAR, BAR+2KB) and are re-zeroed every call (in-graph)
  hipMemsetAsync(BAR, 0, 8192, stream);

  // fp32 -> bf16 conversions
  cvt_f32_bf16<<<dim3(8192), 256, 0, stream>>>((const float4*)x,    (ushort4*)XBF,  2097152);
  cvt_f32_bf16<<<dim3(256),  256, 0, stream>>>((const float4*)wih0, (ushort4*)WIH0, 65536);
  cvt_f32_bf16<<<dim3(1024), 256, 0, stream>>>((const float4*)whh0, (ushort4*)WHH0, 262144);
  cvt_f32_bf16<<<dim3(1024), 256, 0, stream>>>((const float4*)wih1, (ushort4*)WIH1, 262144);
  cvt_f32_bf16<<<dim3(1024), 256, 0, stream>>>((const float4*)whh1, (ushort4*)WHH1, 262144);
  cvt_f32_bf16<<<dim3(256),  256, 0, stream>>>((const float4*)fcw,  (ushort4*)FCW,  65536);
  bias_sum<<<dim3(4), 256, 0, stream>>>(bih0, bhh0, BIAS0, H_);
  bias_sum<<<dim3(4), 256, 0, stream>>>(bih1, bhh1, BIAS1, H_);

  // xp0 = x @ Wih0^T + (bih0+bhh0)   [M=32768, N=1024, K=256]
  gemm_bt<0><<<dim3(8, 256), 256, 0, stream>>>(XBF, WIH0, BIAS0, XP, H_, I_);
  // fused 2-layer scan (513 supersteps); final h2 lands in H2PP slot 1
  rnn_fused<<<dim3(128), 512, 0, stream>>>(WHH0, WIH1, WHH1, XP, BIAS1, H1PP, H2PP, BAR);
  // out = h2_last @ fcW^T + fcb
  fc_kernel<<<dim3(16, 4), 64, 0, stream>>>(H2PP + (size_t)B_*H_, FCW, fcb, (float*)d_out);
}

// Round 12
// 2215.754 us; speedup vs baseline: 3.0105x; 1.3569x over previous
//
#include <hip/hip_runtime.h>
#include <cstdint>
#include <cstddef>

// ---------- types ----------
typedef __attribute__((ext_vector_type(8))) short short8;   // 8 bf16 in 4 VGPRs
typedef __attribute__((ext_vector_type(4))) float f32x4;

#define B_ 64
#define T_ 512
#define I_ 256
#define H_ 1024
#define O_ 256

__device__ __forceinline__ unsigned short f32_to_bf16(float f) {
  unsigned int u = __float_as_uint(f);
  u += 0x7fffu + ((u >> 16) & 1u);           // RNE
  return (unsigned short)(u >> 16);
}
__device__ __forceinline__ float bf16_to_f32(unsigned short h) {
  return __uint_as_float(((unsigned int)h) << 16);
}

__device__ __forceinline__ void gload_lds16(const void* g, void* l) {
  __builtin_amdgcn_global_load_lds((const __attribute__((address_space(1))) void*)g,
                                   (__attribute__((address_space(3))) void*)l, 16, 0, 0);
}

// MALL-write-through stores (bypass L1/L2 -> no cache maintenance ever needed)
__device__ __forceinline__ void store_short_sc(void* p, unsigned short v) {
  unsigned int vv = v;
  asm volatile("global_store_short %0, %1, off sc0 sc1" :: "v"(p), "v"(vv) : "memory");
}
__device__ __forceinline__ void store_int_sc(void* p, int v) {
  asm volatile("global_store_dword %0, %1, off sc0 sc1" :: "v"(p), "v"(v) : "memory");
}
// MALL-coherent 16B load (inline asm: caller MUST s_waitcnt vmcnt before use!)
__device__ __forceinline__ short8 load16_sc(const void* p) {
  short8 r;
  asm volatile("global_load_dwordx4 %0, %1, off sc0 sc1" : "=v"(r) : "v"(p) : "memory");
  return r;
}
// pinned (non-rematerializable) 16B load: executes exactly once (cached path ok)
__device__ __forceinline__ short8 pinned_load16(const void* p) {
  short8 r;
  asm volatile("global_load_dwordx4 %0, %1, off" : "=v"(r) : "v"(p));
  return r;
}

// ---------- conversion kernels ----------
__global__ void cvt_f32_bf16(const float4* __restrict__ s, ushort4* __restrict__ d, int n4) {
  int i = blockIdx.x * blockDim.x + threadIdx.x;
  if (i >= n4) return;
  float4 v = s[i];
  ushort4 o;
  o.x = f32_to_bf16(v.x); o.y = f32_to_bf16(v.y);
  o.z = f32_to_bf16(v.z); o.w = f32_to_bf16(v.w);
  d[i] = o;
}

__global__ void bias_sum(const float* __restrict__ a, const float* __restrict__ b,
                         float* __restrict__ o, int n) {
  int i = blockIdx.x * blockDim.x + threadIdx.x;
  if (i < n) o[i] = a[i] + b[i];
}

// ---------- GEMM: C[M,N] = A[M,K] @ Bm[N,K]^T + bias, 128x128 tile (m97 structure) ----------
template<int OUT_F32>
__global__ __launch_bounds__(256) void gemm_bt(
    const unsigned short* __restrict__ A, const unsigned short* __restrict__ Bm,
    const float* __restrict__ bias, void* __restrict__ Cout, int N_, int K_)
{
  __shared__ unsigned short As[128*32];
  __shared__ unsigned short Bs[128*32];
  const int tid = threadIdx.x;
  const int l = tid & 63, w = tid >> 6;
  const int row0 = blockIdx.y * 128, col0 = blockIdx.x * 128;
  const int wr = w >> 1, wc = w & 1;          // 2x2 waves, each 64x64
  const int lrow = l & 15, lk8 = (l >> 4) * 8;

  f32x4 acc[4][4] = {};

  const int nkb = K_ >> 5;
  for (int kb = 0; kb < nkb; ++kb) {
    #pragma unroll
    for (int c = 0; c < 2; ++c) {
      const int off = w*2048 + c*1024 + l*16;   // byte offset within 8KB tile
      const int row = off >> 6, colb = off & 63;
      gload_lds16((const char*)A  + ((size_t)(row0+row)*K_ + kb*32)*2 + colb,
                  (char*)As + w*2048 + c*1024);
      gload_lds16((const char*)Bm + ((size_t)(col0+row)*K_ + kb*32)*2 + colb,
                  (char*)Bs + w*2048 + c*1024);
    }
    __syncthreads();
    short8 af[4], bfr[4];
    #pragma unroll
    for (int m=0;m<4;++m) af[m]  = *(const short8*)&As[(wr*64 + m*16 + lrow)*32 + lk8];
    #pragma unroll
    for (int n=0;n<4;++n) bfr[n] = *(const short8*)&Bs[(wc*64 + n*16 + lrow)*32 + lk8];
    #pragma unroll
    for (int m=0;m<4;++m)
      #pragma unroll
      for (int n=0;n<4;++n)
        acc[m][n] = __builtin_amdgcn_mfma_f32_16x16x32_bf16(af[m], bfr[n], acc[m][n], 0,0,0);
    __syncthreads();
  }

  #pragma unroll
  for (int n=0;n<4;++n) {
    const int col = col0 + wc*64 + n*16 + lrow;
    const float bv = bias[col];
    #pragma unroll
    for (int m=0;m<4;++m) {
      const int rowb = row0 + wr*64 + m*16 + (l>>4)*4;
      #pragma unroll
      for (int r=0;r<4;++r) {
        const float v = acc[m][n][r] + bv;
        if (OUT_F32) ((float*)Cout)[(size_t)(rowb+r)*N_ + col] = v;
        else ((unsigned short*)Cout)[(size_t)(rowb+r)*N_ + col] = f32_to_bf16(v);
      }
    }
  }
}

// ---------- fused decoupled 2-layer RNN ----------
// 256 wgs x 512 threads, LB(512,2) — 1 wg/CU on all 256 CUs.
// wgs 0-127: LAYER 0 = r5's proven scan (sg=wg&15: 4 samples, rgO=wg>>4: 128
//   cols, 8 waves x 16 cols, Whh0 pinned 128 regs, own 8-wg flag chain at
//   2.42us/step). Publishes flags0[sg*16+rgO]=t+1 for ALL t (incl 511).
//   Writes full H1[B][T][H] via sc stores. NEVER waits on L1.
// wgs 128-255: LAYER 1, self-paced: sg1=lw>>4 (8 samples), rgO1=lw&15 (64
//   cols). Wave-role split: waves 0-3 pin Wih1 rows (128 regs) -> aI =
//   h1_s@Wih1^T; waves 4-7 pin Whh1 (128 regs) -> aH = h2_{s-1}@Whh1^T,
//   handed to waves 0-3 via a 2KB LDS combine buffer. ZERO per-step weight
//   traffic. Polls flags0 (L0, monotone, lag-tolerant via full H1 buffer) and
//   its own flags1 chain (16-wg fan-in, r5 skeleton).
// Deadlock-free: L1 waits only on L0 (always progresses) + own group's
// previous step (inductive). h2 ping-pong overwrite fenced by flags1 chain.
#define L0_STEP(tcur, XREG)                                                          \
  {                                                                                  \
    const int t = (tcur);                                                            \
    f32x4 acc0 = {}, acc1 = {}, acc2 = {}, acc3 = {};                                \
    if (t > 0) {                                                                     \
      _Pragma("unroll")                                                              \
      for (int kk = 0; kk < 32; kk += 4) {                                           \
        short8 a0 = *(const short8*)&lds_h1[arow][(kk+0)*32 + lk8];                  \
        short8 a1 = *(const short8*)&lds_h1[arow][(kk+1)*32 + lk8];                  \
        short8 a2 = *(const short8*)&lds_h1[arow][(kk+2)*32 + lk8];                  \
        short8 a3 = *(const short8*)&lds_h1[arow][(kk+3)*32 + lk8];                  \
        acc0 = __builtin_amdgcn_mfma_f32_16x16x32_bf16(a0, breg[kk+0], acc0, 0,0,0); \
        acc1 = __builtin_amdgcn_mfma_f32_16x16x32_bf16(a1, breg[kk+1], acc1, 0,0,0); \
        acc2 = __builtin_amdgcn_mfma_f32_16x16x32_bf16(a2, breg[kk+2], acc2, 0,0,0); \
        acc3 = __builtin_amdgcn_mfma_f32_16x16x32_bf16(a3, breg[kk+3], acc3, 0,0,0); \
      }                                                                              \
    }                                                                                \
    if (l < 16) {                                                                    \
      _Pragma("unroll")                                                              \
      for (int r = 0; r < 4; ++r) {                                                  \
        const int s = sg*4 + r;                                                      \
        float v = acc0[r] + acc1[r] + acc2[r] + acc3[r]                              \
                + bf16_to_f32((unsigned short)XREG[r]);                              \
        v = fmaxf(v, 0.f);                                                           \
        store_short_sc(h1buf + ((size_t)s*T_ + t)*H_ + col, f32_to_bf16(v));         \
      }                                                                              \
    }                                                                                \
    asm volatile("s_waitcnt vmcnt(0)" ::: "memory");     /* h1 stores at MALL */     \
    __syncthreads();                                     /* all 8 waves drained */   \
    if (tid == 0) store_int_sc(&flags0g[rgO], t+1);      /* publish ALL t */         \
    if (t < T_-1) {                                                                  \
      { int fv;                                                                      \
        do { fv = __hip_atomic_load(flags0g + (l & 7), __ATOMIC_RELAXED,             \
                                    __HIP_MEMORY_SCOPE_AGENT);                       \
        } while (!__all(fv >= t+1)); }                                               \
      const unsigned short* hrow = h1buf + ((size_t)(sg*4 + (w>>1))*T_ + t)*H_;      \
      const int tn = (t+2 < T_) ? (t+2) : (T_-1);                                    \
      const unsigned short* xpp = xp + ((size_t)(sg*4)*T_ + tn)*H_ + col;            \
      short8 sv = load16_sc(hrow + (w&1)*512 + l*8);     /* 1 outstanding */         \
      _Pragma("unroll")                                                              \
      for (int r = 0; r < 4; ++r)                        /* +4 outstanding */        \
        asm volatile("global_load_ushort %0, %1, off"                               \
                     : "=v"(XREG[r]) : "v"(xpp + (size_t)r*T_*H_) : "memory");       \
      asm volatile("s_waitcnt vmcnt(4)" ::: "memory");   /* wait stage load only */  \
      *(short8*)&lds_h1[w>>1][(w&1)*512 + l*8] = sv;                                 \
      __syncthreads();                                   /* LDS visible for t+1 */   \
    }                                                                                \
  }

__global__ __launch_bounds__(512, 2) void rnn_fused(
    const unsigned short* __restrict__ whh0,
    const unsigned short* __restrict__ wih1,
    const unsigned short* __restrict__ whh1,
    const unsigned short* __restrict__ xp,     // xp0 = x@Wih0^T + b  [B][T][H]
    const float* __restrict__ bias1,           // bih1 + bhh1
    unsigned short* __restrict__ h1buf,        // H1 [B][T][H] (full, no overwrite)
    unsigned short* __restrict__ h2pp,         // [2][B][H]; final h2 in slot 1
    int* __restrict__ bar)
{
  // 35,328 B static LDS (r10's 66KB overflow was the crash — stay < 64KB!)
  __shared__ unsigned short lds_h1[8][1040];   // L0 uses rows 0..3 only
  __shared__ unsigned short lds_h2[8][1040];
  __shared__ float comb[4][8][16];             // L1 aH handoff

  const int wg = blockIdx.x;            // 0..255
  const int tid = threadIdx.x;          // 0..511
  const int l = tid & 63;
  const int w = tid >> 6;               // 0..7
  const int lrow = l & 15;
  const int lk8 = (l >> 4) * 8;

  if (wg < 128) {
    // ================= LAYER 0 (r5 verbatim, publish-all-t) =================
    const int sg = wg & 15;             // 4 samples
    const int rgO = wg >> 4;            // 0..7 (128 cols)
    const int col = rgO*128 + w*16 + lrow;
    const int arow = lrow & 3;
    int* flags0g = bar + sg*16;

    short8 breg[32];
    #pragma unroll
    for (int kk=0; kk<32; ++kk)
      breg[kk] = pinned_load16(&whh0[(size_t)col*H_ + kk*32 + lk8]);

    unsigned int xa[4], xb[4];
    #pragma unroll
    for (int r=0; r<4; ++r) {
      asm volatile("global_load_ushort %0, %1, off" : "=v"(xa[r])
        : "v"(xp + ((size_t)(sg*4+r)*T_ + 0)*H_ + col) : "memory");
      asm volatile("global_load_ushort %0, %1, off" : "=v"(xb[r])
        : "v"(xp + ((size_t)(sg*4+r)*T_ + 1)*H_ + col) : "memory");
    }
    asm volatile("s_waitcnt vmcnt(0)" ::: "memory");
    __builtin_amdgcn_sched_barrier(0);

    for (int t2 = 0; t2 < T_; t2 += 2) {
      L0_STEP(t2,   xa);
      L0_STEP(t2+1, xb);
    }
  } else {
    // ================= LAYER 1 (wave-role split, self-paced) =================
    const int lw = wg - 128;
    const int sg1 = lw >> 4;            // 0..7 (8 samples)
    const int rgO1 = lw & 15;           // 0..15 (64 cols)
    const int q = w & 3;                // col quad within wg
    const bool isI = (w < 4);           // waves 0-3: Wih1; 4-7: Whh1
    const int col = rgO1*64 + q*16 + lrow;
    const int arow = lrow & 7;          // 8 samples dup to 16 rows
    int* flags1g = bar + 1024 + sg1*16;
    const int fi0 = (2*sg1 + ((l>>3)&1))*16 + (l&7);   // L0 flags for my samples

    const unsigned short* wsel = isI ? wih1 : whh1;
    short8 breg[32];
    #pragma unroll
    for (int kk=0; kk<32; ++kk)
      breg[kk] = pinned_load16(&wsel[(size_t)col*H_ + kk*32 + lk8]);
    asm volatile("s_waitcnt vmcnt(0)" ::: "memory");
    __builtin_amdgcn_sched_barrier(0);

    const float b1v = bias1[col];

    // prologue: wait h1_0, stage into lds_h1 (wave w -> sample row w)
    { int fv;
      do { fv = __hip_atomic_load(bar + fi0, __ATOMIC_RELAXED,
                                  __HIP_MEMORY_SCOPE_AGENT);
      } while (!__all(fv >= 1)); }
    {
      short8 s0 = load16_sc(h1buf + ((size_t)(sg1*8 + w)*T_ + 0)*H_ + l*8);
      short8 s1 = load16_sc(h1buf + ((size_t)(sg1*8 + w)*T_ + 0)*H_ + 512 + l*8);
      asm volatile("s_waitcnt vmcnt(0)" ::: "memory");
      *(short8*)&lds_h1[w][l*8]       = s0;
      *(short8*)&lds_h1[w][512 + l*8] = s1;
      __syncthreads();
    }

    for (int s = 0; s < T_; ++s) {
      f32x4 a0 = {}, a1 = {};
      if (isI) {
        #pragma unroll
        for (int kk = 0; kk < 32; kk += 2) {
          short8 x0 = *(const short8*)&lds_h1[arow][(kk+0)*32 + lk8];
          short8 x1 = *(const short8*)&lds_h1[arow][(kk+1)*32 + lk8];
          a0 = __builtin_amdgcn_mfma_f32_16x16x32_bf16(x0, breg[kk+0], a0, 0,0,0);
          a1 = __builtin_amdgcn_mfma_f32_16x16x32_bf16(x1, breg[kk+1], a1, 0,0,0);
        }
      } else {
        if (s > 0) {
          #pragma unroll
          for (int kk = 0; kk < 32; kk += 2) {
            short8 x0 = *(const short8*)&lds_h2[arow][(kk+0)*32 + lk8];
            short8 x1 = *(const short8*)&lds_h2[arow][(kk+1)*32 + lk8];
            a0 = __builtin_amdgcn_mfma_f32_16x16x32_bf16(x0, breg[kk+0], a0, 0,0,0);
            a1 = __builtin_amdgcn_mfma_f32_16x16x32_bf16(x1, breg[kk+1], a1, 0,0,0);
          }
        }
        if (l < 32) {
          #pragma unroll
          for (int r = 0; r < 4; ++r)
            comb[q][(l>>4)*4 + r][lrow] = a0[r] + a1[r];
        }
      }
      __syncthreads();                                   // comb visible
      if (isI && l < 32) {
        #pragma unroll
        for (int r = 0; r < 4; ++r) {
          const int smp = sg1*8 + (l>>4)*4 + r;
          float v = a0[r] + a1[r] + comb[q][(l>>4)*4 + r][lrow] + b1v;
          v = fmaxf(v, 0.f);
          store_short_sc(h2pp + ((size_t)((s&1)*B_ + smp))*H_ + col, f32_to_bf16(v));
        }
      }
      asm volatile("s_waitcnt vmcnt(0)" ::: "memory");   // h2 stores at MALL
      __syncthreads();                                    // all 8 waves drained
      if (tid == 0) store_int_sc(&flags1g[rgO1], s+1);
      if (s < T_-1) {
        { int v0, v1;
          do {
            v0 = __hip_atomic_load(bar + fi0, __ATOMIC_RELAXED,
                                   __HIP_MEMORY_SCOPE_AGENT);
            v1 = __hip_atomic_load(flags1g + (l & 15), __ATOMIC_RELAXED,
                                   __HIP_MEMORY_SCOPE_AGENT);
          } while (!(__all(v0 >= s+2) && __all(v1 >= s+1))); }
        // stage h1_{s+1} row w and h2_s row w (4 sc loads/lane)
        short8 t0 = load16_sc(h1buf + ((size_t)(sg1*8 + w)*T_ + (s+1))*H_ + l*8);
        short8 t1 = load16_sc(h1buf + ((size_t)(sg1*8 + w)*T_ + (s+1))*H_ + 512 + l*8);
        short8 t2 = load16_sc(h2pp + ((size_t)((s&1)*B_ + sg1*8 + w))*H_ + l*8);
        short8 t3 = load16_sc(h2pp + ((size_t)((s&1)*B_ + sg1*8 + w))*H_ + 512 + l*8);
        asm volatile("s_waitcnt vmcnt(0)" ::: "memory");
        *(short8*)&lds_h1[w][l*8]       = t0;
        *(short8*)&lds_h1[w][512 + l*8] = t1;
        *(short8*)&lds_h2[w][l*8]       = t2;
        *(short8*)&lds_h2[w][512 + l*8] = t3;
        __syncthreads();
      }
    }
  }
}

// ---------- final FC: out[64,256] = h2 @ fcW^T + fcb (f32 out) ----------
__global__ __launch_bounds__(64) void fc_kernel(const unsigned short* __restrict__ h,
                                                const unsigned short* __restrict__ fw,
                                                const float* __restrict__ fb,
                                                float* __restrict__ out) {
  const int l = threadIdx.x;
  const int bx = blockIdx.x, by = blockIdx.y;   // bx: 16 col tiles, by: 4 row tiles
  const int lrow = l & 15, lk8 = (l>>4)*8;
  f32x4 acc = {};
  #pragma unroll
  for (int kk=0; kk<32; ++kk) {
    short8 a = *(const short8*)&h [(size_t)(by*16 + lrow)*H_ + kk*32 + lk8];
    short8 b = *(const short8*)&fw[(size_t)(bx*16 + lrow)*H_ + kk*32 + lk8];
    acc = __builtin_amdgcn_mfma_f32_16x16x32_bf16(a, b, acc, 0,0,0);
  }
  const int col = bx*16 + lrow;
  const float bv = fb[col];
  #pragma unroll
  for (int r=0;r<4;++r) {
    const int row = by*16 + (l>>4)*4 + r;
    out[row*O_ + col] = acc[r] + bv;
  }
}

// ---------- launch ----------
extern "C" void kernel_launch(void* const* d_in, const int* in_sizes, int n_in,
                              void* d_out, int out_size, void* d_ws, size_t ws_size,
                              hipStream_t stream) {
  const float* x    = (const float*)d_in[0];
  const float* wih0 = (const float*)d_in[1];
  const float* bih0 = (const float*)d_in[2];
  const float* whh0 = (const float*)d_in[3];
  const float* bhh0 = (const float*)d_in[4];
  const float* wih1 = (const float*)d_in[5];
  const float* bih1 = (const float*)d_in[6];
  const float* whh1 = (const float*)d_in[7];
  const float* bhh1 = (const float*)d_in[8];
  const float* fcw  = (const float*)d_in[9];
  const float* fcb  = (const float*)d_in[10];

  char* ws = (char*)d_ws;
  // workspace layout (bytes)
  unsigned short* XBF  = (unsigned short*)(ws + 0);          // 16,777,216  x bf16
  unsigned short* WIH0 = (unsigned short*)(ws + 16777216);   //    524,288
  unsigned short* WHH0 = (unsigned short*)(ws + 17301504);   //  2,097,152
  unsigned short* WIH1 = (unsigned short*)(ws + 19398656);   //  2,097,152
  unsigned short* WHH1 = (unsigned short*)(ws + 21495808);   //  2,097,152
  unsigned short* FCW  = (unsigned short*)(ws + 23592960);   //    524,288
  float*          BIAS0= (float*)(ws + 24117248);            //      4,096
  float*          BIAS1= (float*)(ws + 24121344);            //      4,096
  unsigned short* XP   = (unsigned short*)(ws + 24125440);   // 67,108,864  xp0 [B][T][H]
  unsigned short* H1   = (unsigned short*)(ws + 91234304);   // 67,108,864  h1 [B][T][H]
  unsigned short* H2PP = (unsigned short*)(ws + 158343168);  //    262,144  h2 ping-pong
  int*            BAR  = (int*)(ws + 158605312);             //      8,192  flag lines

  // flags0 at BAR[0..255], flags1 at BAR[1024..1151] — all re-zeroed in-graph
  hipMemsetAsync(BAR, 0, 8192, stream);

  // fp32 -> bf16 conversions
  cvt_f32_bf16<<<dim3(8192), 256, 0, stream>>>((const float4*)x,    (ushort4*)XBF,  2097152);
  cvt_f32_bf16<<<dim3(256),  256, 0, stream>>>((const float4*)wih0, (ushort4*)WIH0, 65536);
  cvt_f32_bf16<<<dim3(1024), 256, 0, stream>>>((const float4*)whh0, (ushort4*)WHH0, 262144);
  cvt_f32_bf16<<<dim3(1024), 256, 0, stream>>>((const float4*)wih1, (ushort4*)WIH1, 262144);
  cvt_f32_bf16<<<dim3(1024), 256, 0, stream>>>((const float4*)whh1, (ushort4*)WHH1, 262144);
  cvt_f32_bf16<<<dim3(256),  256, 0, stream>>>((const float4*)fcw,  (ushort4*)FCW,  65536);
  bias_sum<<<dim3(4), 256, 0, stream>>>(bih0, bhh0, BIAS0, H_);
  bias_sum<<<dim3(4), 256, 0, stream>>>(bih1, bhh1, BIAS1, H_);

  // xp0 = x @ Wih0^T + (bih0+bhh0)   [M=32768, N=1024, K=256]
  gemm_bt<0><<<dim3(8, 256), 256, 0, stream>>>(XBF, WIH0, BIAS0, XP, H_, I_);
  // fused decoupled 2-layer scan; final h2 lands in H2PP slot 1
  rnn_fused<<<dim3(256), 512, 0, stream>>>(WHH0, WIH1, WHH1, XP, BIAS1, H1, H2PP, BAR);
  // out = h2_last @ fcW^T + fcb
  fc_kernel<<<dim3(16, 4), 64, 0, stream>>>(H2PP + (size_t)B_*H_, FCW, fcb, (float*)d_out);
}

// Round 13
// 2095.701 us; speedup vs baseline: 3.1830x; 1.0573x over previous
//
#include <hip/hip_runtime.h>
#include <cstdint>
#include <cstddef>

// ---------- types ----------
typedef __attribute__((ext_vector_type(8))) short short8;   // 8 bf16 in 4 VGPRs
typedef __attribute__((ext_vector_type(4))) float f32x4;

#define B_ 64
#define T_ 512
#define I_ 256
#define H_ 1024
#define O_ 256

__device__ __forceinline__ unsigned short f32_to_bf16(float f) {
  unsigned int u = __float_as_uint(f);
  u += 0x7fffu + ((u >> 16) & 1u);           // RNE
  return (unsigned short)(u >> 16);
}
__device__ __forceinline__ float bf16_to_f32(unsigned short h) {
  return __uint_as_float(((unsigned int)h) << 16);
}

__device__ __forceinline__ void gload_lds16(const void* g, void* l) {
  __builtin_amdgcn_global_load_lds((const __attribute__((address_space(1))) void*)g,
                                   (__attribute__((address_space(3))) void*)l, 16, 0, 0);
}

// MALL-write-through stores (bypass L1/L2 -> no cache maintenance ever needed)
__device__ __forceinline__ void store_short_sc(void* p, unsigned short v) {
  unsigned int vv = v;
  asm volatile("global_store_short %0, %1, off sc0 sc1" :: "v"(p), "v"(vv) : "memory");
}
__device__ __forceinline__ void store_int_sc(void* p, int v) {
  asm volatile("global_store_dword %0, %1, off sc0 sc1" :: "v"(p), "v"(v) : "memory");
}
// MALL-coherent 16B load (inline asm: caller MUST s_waitcnt vmcnt before use!)
__device__ __forceinline__ short8 load16_sc(const void* p) {
  short8 r;
  asm volatile("global_load_dwordx4 %0, %1, off sc0 sc1" : "=v"(r) : "v"(p) : "memory");
  return r;
}
// pinned (non-rematerializable) 16B load: executes exactly once (cached path ok)
__device__ __forceinline__ short8 pinned_load16(const void* p) {
  short8 r;
  asm volatile("global_load_dwordx4 %0, %1, off" : "=v"(r) : "v"(p));
  return r;
}

// ---------- conversion kernels ----------
__global__ void cvt_f32_bf16(const float4* __restrict__ s, ushort4* __restrict__ d, int n4) {
  int i = blockIdx.x * blockDim.x + threadIdx.x;
  if (i >= n4) return;
  float4 v = s[i];
  ushort4 o;
  o.x = f32_to_bf16(v.x); o.y = f32_to_bf16(v.y);
  o.z = f32_to_bf16(v.z); o.w = f32_to_bf16(v.w);
  d[i] = o;
}

__global__ void bias_sum(const float* __restrict__ a, const float* __restrict__ b,
                         float* __restrict__ o, int n) {
  int i = blockIdx.x * blockDim.x + threadIdx.x;
  if (i < n) o[i] = a[i] + b[i];
}

// ---------- GEMM: C[M,N] = A[M,K] @ Bm[N,K]^T + bias, 128x128 tile (m97 structure) ----------
template<int OUT_F32>
__global__ __launch_bounds__(256) void gemm_bt(
    const unsigned short* __restrict__ A, const unsigned short* __restrict__ Bm,
    const float* __restrict__ bias, void* __restrict__ Cout, int N_, int K_)
{
  __shared__ unsigned short As[128*32];
  __shared__ unsigned short Bs[128*32];
  const int tid = threadIdx.x;
  const int l = tid & 63, w = tid >> 6;
  const int row0 = blockIdx.y * 128, col0 = blockIdx.x * 128;
  const int wr = w >> 1, wc = w & 1;          // 2x2 waves, each 64x64
  const int lrow = l & 15, lk8 = (l >> 4) * 8;

  f32x4 acc[4][4] = {};

  const int nkb = K_ >> 5;
  for (int kb = 0; kb < nkb; ++kb) {
    #pragma unroll
    for (int c = 0; c < 2; ++c) {
      const int off = w*2048 + c*1024 + l*16;   // byte offset within 8KB tile
      const int row = off >> 6, colb = off & 63;
      gload_lds16((const char*)A  + ((size_t)(row0+row)*K_ + kb*32)*2 + colb,
                  (char*)As + w*2048 + c*1024);
      gload_lds16((const char*)Bm + ((size_t)(col0+row)*K_ + kb*32)*2 + colb,
                  (char*)Bs + w*2048 + c*1024);
    }
    __syncthreads();
    short8 af[4], bfr[4];
    #pragma unroll
    for (int m=0;m<4;++m) af[m]  = *(const short8*)&As[(wr*64 + m*16 + lrow)*32 + lk8];
    #pragma unroll
    for (int n=0;n<4;++n) bfr[n] = *(const short8*)&Bs[(wc*64 + n*16 + lrow)*32 + lk8];
    #pragma unroll
    for (int m=0;m<4;++m)
      #pragma unroll
      for (int n=0;n<4;++n)
        acc[m][n] = __builtin_amdgcn_mfma_f32_16x16x32_bf16(af[m], bfr[n], acc[m][n], 0,0,0);
    __syncthreads();
  }

  #pragma unroll
  for (int n=0;n<4;++n) {
    const int col = col0 + wc*64 + n*16 + lrow;
    const float bv = bias[col];
    #pragma unroll
    for (int m=0;m<4;++m) {
      const int rowb = row0 + wr*64 + m*16 + (l>>4)*4;
      #pragma unroll
      for (int r=0;r<4;++r) {
        const float v = acc[m][n][r] + bv;
        if (OUT_F32) ((float*)Cout)[(size_t)(rowb+r)*N_ + col] = v;
        else ((unsigned short*)Cout)[(size_t)(rowb+r)*N_ + col] = f32_to_bf16(v);
      }
    }
  }
}

// ---------- fused decoupled 2-layer RNN ----------
// 256 wgs x 512 threads, LB(512,2) — 1 wg/CU on all 256 CUs.
// wgs 0-127: LAYER 0 = r5's proven scan. wgs 128-255: LAYER 1 wave-role split
// (waves 0-3 pin Wih1, waves 4-7 pin Whh1, LDS comb handoff).
// r13 delta (L1 wait/stage path only):
//   - POLL SPLIT: single-load poll on flags0 (>=s+2, L0 leads -> instant), then
//     single-load poll on flags1 (one MALL RT per iteration, not two).
//   - h1 PREFETCH OVERLAP: h1_{s+1} sc-loads issued BETWEEN the polls; their
//     MALL RT drains in parallel with the flags1 observe.
#define L0_STEP(tcur, XREG)                                                          \
  {                                                                                  \
    const int t = (tcur);                                                            \
    f32x4 acc0 = {}, acc1 = {}, acc2 = {}, acc3 = {};                                \
    if (t > 0) {                                                                     \
      _Pragma("unroll")                                                              \
      for (int kk = 0; kk < 32; kk += 4) {                                           \
        short8 a0 = *(const short8*)&lds_h1[arow][(kk+0)*32 + lk8];                  \
        short8 a1 = *(const short8*)&lds_h1[arow][(kk+1)*32 + lk8];                  \
        short8 a2 = *(const short8*)&lds_h1[arow][(kk+2)*32 + lk8];                  \
        short8 a3 = *(const short8*)&lds_h1[arow][(kk+3)*32 + lk8];                  \
        acc0 = __builtin_amdgcn_mfma_f32_16x16x32_bf16(a0, breg[kk+0], acc0, 0,0,0); \
        acc1 = __builtin_amdgcn_mfma_f32_16x16x32_bf16(a1, breg[kk+1], acc1, 0,0,0); \
        acc2 = __builtin_amdgcn_mfma_f32_16x16x32_bf16(a2, breg[kk+2], acc2, 0,0,0); \
        acc3 = __builtin_amdgcn_mfma_f32_16x16x32_bf16(a3, breg[kk+3], acc3, 0,0,0); \
      }                                                                              \
    }                                                                                \
    if (l < 16) {                                                                    \
      _Pragma("unroll")                                                              \
      for (int r = 0; r < 4; ++r) {                                                  \
        const int s = sg*4 + r;                                                      \
        float v = acc0[r] + acc1[r] + acc2[r] + acc3[r]                              \
                + bf16_to_f32((unsigned short)XREG[r]);                              \
        v = fmaxf(v, 0.f);                                                           \
        store_short_sc(h1buf + ((size_t)s*T_ + t)*H_ + col, f32_to_bf16(v));         \
      }                                                                              \
    }                                                                                \
    asm volatile("s_waitcnt vmcnt(0)" ::: "memory");     /* h1 stores at MALL */     \
    __syncthreads();                                     /* all 8 waves drained */   \
    if (tid == 0) store_int_sc(&flags0g[rgO], t+1);      /* publish ALL t */         \
    if (t < T_-1) {                                                                  \
      { int fv;                                                                      \
        do { fv = __hip_atomic_load(flags0g + (l & 7), __ATOMIC_RELAXED,             \
                                    __HIP_MEMORY_SCOPE_AGENT);                       \
        } while (!__all(fv >= t+1)); }                                               \
      const unsigned short* hrow = h1buf + ((size_t)(sg*4 + (w>>1))*T_ + t)*H_;      \
      const int tn = (t+2 < T_) ? (t+2) : (T_-1);                                    \
      const unsigned short* xpp = xp + ((size_t)(sg*4)*T_ + tn)*H_ + col;            \
      short8 sv = load16_sc(hrow + (w&1)*512 + l*8);     /* 1 outstanding */         \
      _Pragma("unroll")                                                              \
      for (int r = 0; r < 4; ++r)                        /* +4 outstanding */        \
        asm volatile("global_load_ushort %0, %1, off"                               \
                     : "=v"(XREG[r]) : "v"(xpp + (size_t)r*T_*H_) : "memory");       \
      asm volatile("s_waitcnt vmcnt(4)" ::: "memory");   /* wait stage load only */  \
      *(short8*)&lds_h1[w>>1][(w&1)*512 + l*8] = sv;                                 \
      __syncthreads();                                   /* LDS visible for t+1 */   \
    }                                                                                \
  }

__global__ __launch_bounds__(512, 2) void rnn_fused(
    const unsigned short* __restrict__ whh0,
    const unsigned short* __restrict__ wih1,
    const unsigned short* __restrict__ whh1,
    const unsigned short* __restrict__ xp,     // xp0 = x@Wih0^T + b  [B][T][H]
    const float* __restrict__ bias1,           // bih1 + bhh1
    unsigned short* __restrict__ h1buf,        // H1 [B][T][H] (full, no overwrite)
    unsigned short* __restrict__ h2pp,         // [2][B][H]; final h2 in slot 1
    int* __restrict__ bar)
{
  // 35,328 B static LDS (stay < 64KB — r10 lesson)
  __shared__ unsigned short lds_h1[8][1040];   // L0 uses rows 0..3 only
  __shared__ unsigned short lds_h2[8][1040];
  __shared__ float comb[4][8][16];             // L1 aH handoff

  const int wg = blockIdx.x;            // 0..255
  const int tid = threadIdx.x;          // 0..511
  const int l = tid & 63;
  const int w = tid >> 6;               // 0..7
  const int lrow = l & 15;
  const int lk8 = (l >> 4) * 8;

  if (wg < 128) {
    // ================= LAYER 0 (r5 verbatim, publish-all-t) =================
    const int sg = wg & 15;             // 4 samples
    const int rgO = wg >> 4;            // 0..7 (128 cols)
    const int col = rgO*128 + w*16 + lrow;
    const int arow = lrow & 3;
    int* flags0g = bar + sg*16;

    short8 breg[32];
    #pragma unroll
    for (int kk=0; kk<32; ++kk)
      breg[kk] = pinned_load16(&whh0[(size_t)col*H_ + kk*32 + lk8]);

    unsigned int xa[4], xb[4];
    #pragma unroll
    for (int r=0; r<4; ++r) {
      asm volatile("global_load_ushort %0, %1, off" : "=v"(xa[r])
        : "v"(xp + ((size_t)(sg*4+r)*T_ + 0)*H_ + col) : "memory");
      asm volatile("global_load_ushort %0, %1, off" : "=v"(xb[r])
        : "v"(xp + ((size_t)(sg*4+r)*T_ + 1)*H_ + col) : "memory");
    }
    asm volatile("s_waitcnt vmcnt(0)" ::: "memory");
    __builtin_amdgcn_sched_barrier(0);

    for (int t2 = 0; t2 < T_; t2 += 2) {
      L0_STEP(t2,   xa);
      L0_STEP(t2+1, xb);
    }
  } else {
    // ================= LAYER 1 (wave-role split, self-paced) =================
    const int lw = wg - 128;
    const int sg1 = lw >> 4;            // 0..7 (8 samples)
    const int rgO1 = lw & 15;           // 0..15 (64 cols)
    const int q = w & 3;                // col quad within wg
    const bool isI = (w < 4);           // waves 0-3: Wih1; 4-7: Whh1
    const int col = rgO1*64 + q*16 + lrow;
    const int arow = lrow & 7;          // 8 samples dup to 16 rows
    int* flags1g = bar + 1024 + sg1*16;
    const int fi0 = (2*sg1 + ((l>>3)&1))*16 + (l&7);   // L0 flags for my samples

    const unsigned short* wsel = isI ? wih1 : whh1;
    short8 breg[32];
    #pragma unroll
    for (int kk=0; kk<32; ++kk)
      breg[kk] = pinned_load16(&wsel[(size_t)col*H_ + kk*32 + lk8]);
    asm volatile("s_waitcnt vmcnt(0)" ::: "memory");
    __builtin_amdgcn_sched_barrier(0);

    const float b1v = bias1[col];

    // prologue: wait h1_0, stage into lds_h1 (wave w -> sample row w)
    { int fv;
      do { fv = __hip_atomic_load(bar + fi0, __ATOMIC_RELAXED,
                                  __HIP_MEMORY_SCOPE_AGENT);
      } while (!__all(fv >= 1)); }
    {
      short8 s0 = load16_sc(h1buf + ((size_t)(sg1*8 + w)*T_ + 0)*H_ + l*8);
      short8 s1 = load16_sc(h1buf + ((size_t)(sg1*8 + w)*T_ + 0)*H_ + 512 + l*8);
      asm volatile("s_waitcnt vmcnt(0)" ::: "memory");
      *(short8*)&lds_h1[w][l*8]       = s0;
      *(short8*)&lds_h1[w][512 + l*8] = s1;
      __syncthreads();
    }

    for (int s = 0; s < T_; ++s) {
      f32x4 a0 = {}, a1 = {};
      if (isI) {
        #pragma unroll
        for (int kk = 0; kk < 32; kk += 2) {
          short8 x0 = *(const short8*)&lds_h1[arow][(kk+0)*32 + lk8];
          short8 x1 = *(const short8*)&lds_h1[arow][(kk+1)*32 + lk8];
          a0 = __builtin_amdgcn_mfma_f32_16x16x32_bf16(x0, breg[kk+0], a0, 0,0,0);
          a1 = __builtin_amdgcn_mfma_f32_16x16x32_bf16(x1, breg[kk+1], a1, 0,0,0);
        }
      } else {
        if (s > 0) {
          #pragma unroll
          for (int kk = 0; kk < 32; kk += 2) {
            short8 x0 = *(const short8*)&lds_h2[arow][(kk+0)*32 + lk8];
            short8 x1 = *(const short8*)&lds_h2[arow][(kk+1)*32 + lk8];
            a0 = __builtin_amdgcn_mfma_f32_16x16x32_bf16(x0, breg[kk+0], a0, 0,0,0);
            a1 = __builtin_amdgcn_mfma_f32_16x16x32_bf16(x1, breg[kk+1], a1, 0,0,0);
          }
        }
        if (l < 32) {
          #pragma unroll
          for (int r = 0; r < 4; ++r)
            comb[q][(l>>4)*4 + r][lrow] = a0[r] + a1[r];
        }
      }
      __syncthreads();                                   // comb visible
      if (isI && l < 32) {
        #pragma unroll
        for (int r = 0; r < 4; ++r) {
          const int smp = sg1*8 + (l>>4)*4 + r;
          float v = a0[r] + a1[r] + comb[q][(l>>4)*4 + r][lrow] + b1v;
          v = fmaxf(v, 0.f);
          store_short_sc(h2pp + ((size_t)((s&1)*B_ + smp))*H_ + col, f32_to_bf16(v));
        }
      }
      asm volatile("s_waitcnt vmcnt(0)" ::: "memory");   // h2 stores at MALL
      __syncthreads();                                    // all 8 waves drained
      if (tid == 0) store_int_sc(&flags1g[rgO1], s+1);
      if (s < T_-1) {
        // ---- r13: split polls + h1 prefetch overlap ----
        // (1) flags0 poll (single load) — L0 leads by many steps; near-instant
        { int v0;
          do { v0 = __hip_atomic_load(bar + fi0, __ATOMIC_RELAXED,
                                      __HIP_MEMORY_SCOPE_AGENT);
          } while (!__all(v0 >= s+2)); }
        // (2) issue h1_{s+1} stage loads — outstanding across the flags1 poll
        short8 t0 = load16_sc(h1buf + ((size_t)(sg1*8 + w)*T_ + (s+1))*H_ + l*8);
        short8 t1 = load16_sc(h1buf + ((size_t)(sg1*8 + w)*T_ + (s+1))*H_ + 512 + l*8);
        // (3) flags1 poll (single load) — h1 RT drains in parallel with observe
        { int v1;
          do { v1 = __hip_atomic_load(flags1g + (l & 15), __ATOMIC_RELAXED,
                                      __HIP_MEMORY_SCOPE_AGENT);
          } while (!__all(v1 >= s+1)); }
        // (4) h2 loads + drain + LDS + sync
        short8 t2 = load16_sc(h2pp + ((size_t)((s&1)*B_ + sg1*8 + w))*H_ + l*8);
        short8 t3 = load16_sc(h2pp + ((size_t)((s&1)*B_ + sg1*8 + w))*H_ + 512 + l*8);
        asm volatile("s_waitcnt vmcnt(0)" ::: "memory");
        *(short8*)&lds_h1[w][l*8]       = t0;
        *(short8*)&lds_h1[w][512 + l*8] = t1;
        *(short8*)&lds_h2[w][l*8]       = t2;
        *(short8*)&lds_h2[w][512 + l*8] = t3;
        __syncthreads();
      }
    }
  }
}

// ---------- final FC: out[64,256] = h2 @ fcW^T + fcb (f32 out) ----------
__global__ __launch_bounds__(64) void fc_kernel(const unsigned short* __restrict__ h,
                                                const unsigned short* __restrict__ fw,
                                                const float* __restrict__ fb,
                                                float* __restrict__ out) {
  const int l = threadIdx.x;
  const int bx = blockIdx.x, by = blockIdx.y;   // bx: 16 col tiles, by: 4 row tiles
  const int lrow = l & 15, lk8 = (l>>4)*8;
  f32x4 acc = {};
  #pragma unroll
  for (int kk=0; kk<32; ++kk) {
    short8 a = *(const short8*)&h [(size_t)(by*16 + lrow)*H_ + kk*32 + lk8];
    short8 b = *(const short8*)&fw[(size_t)(bx*16 + lrow)*H_ + kk*32 + lk8];
    acc = __builtin_amdgcn_mfma_f32_16x16x32_bf16(a, b, acc, 0,0,0);
  }
  const int col = bx*16 + lrow;
  const float bv = fb[col];
  #pragma unroll
  for (int r=0;r<4;++r) {
    const int row = by*16 + (l>>4)*4 + r;
    out[row*O_ + col] = acc[r] + bv;
  }
}

// ---------- launch ----------
extern "C" void kernel_launch(void* const* d_in, const int* in_sizes, int n_in,
                              void* d_out, int out_size, void* d_ws, size_t ws_size,
                              hipStream_t stream) {
  const float* x    = (const float*)d_in[0];
  const float* wih0 = (const float*)d_in[1];
  const float* bih0 = (const float*)d_in[2];
  const float* whh0 = (const float*)d_in[3];
  const float* bhh0 = (const float*)d_in[4];
  const float* wih1 = (const float*)d_in[5];
  const float* bih1 = (const float*)d_in[6];
  const float* whh1 = (const float*)d_in[7];
  const float* bhh1 = (const float*)d_in[8];
  const float* fcw  = (const float*)d_in[9];
  const float* fcb  = (const float*)d_in[10];

  char* ws = (char*)d_ws;
  // workspace layout (bytes)
  unsigned short* XBF  = (unsigned short*)(ws + 0);          // 16,777,216  x bf16
  unsigned short* WIH0 = (unsigned short*)(ws + 16777216);   //    524,288
  unsigned short* WHH0 = (unsigned short*)(ws + 17301504);   //  2,097,152
  unsigned short* WIH1 = (unsigned short*)(ws + 19398656);   //  2,097,152
  unsigned short* WHH1 = (unsigned short*)(ws + 21495808);   //  2,097,152
  unsigned short* FCW  = (unsigned short*)(ws + 23592960);   //    524,288
  float*          BIAS0= (float*)(ws + 24117248);            //      4,096
  float*          BIAS1= (float*)(ws + 24121344);            //      4,096
  unsigned short* XP   = (unsigned short*)(ws + 24125440);   // 67,108,864  xp0 [B][T][H]
  unsigned short* H1   = (unsigned short*)(ws + 91234304);   // 67,108,864  h1 [B][T][H]
  unsigned short* H2PP = (unsigned short*)(ws + 158343168);  //    262,144  h2 ping-pong
  int*            BAR  = (int*)(ws + 158605312);             //      8,192  flag lines

  // flags0 at BAR[0..255], flags1 at BAR[1024..1151] — all re-zeroed in-graph
  hipMemsetAsync(BAR, 0, 8192, stream);

  // fp32 -> bf16 conversions
  cvt_f32_bf16<<<dim3(8192), 256, 0, stream>>>((const float4*)x,    (ushort4*)XBF,  2097152);
  cvt_f32_bf16<<<dim3(256),  256, 0, stream>>>((const float4*)wih0, (ushort4*)WIH0, 65536);
  cvt_f32_bf16<<<dim3(1024), 256, 0, stream>>>((const float4*)whh0, (ushort4*)WHH0, 262144);
  cvt_f32_bf16<<<dim3(1024), 256, 0, stream>>>((const float4*)wih1, (ushort4*)WIH1, 262144);
  cvt_f32_bf16<<<dim3(1024), 256, 0, stream>>>((const float4*)whh1, (ushort4*)WHH1, 262144);
  cvt_f32_bf16<<<dim3(256),  256, 0, stream>>>((const float4*)fcw,  (ushort4*)FCW,  65536);
  bias_sum<<<dim3(4), 256, 0, stream>>>(bih0, bhh0, BIAS0, H_);
  bias_sum<<<dim3(4), 256, 0, stream>>>(bih1, bhh1, BIAS1, H_);

  // xp0 = x @ Wih0^T + (bih0+bhh0)   [M=32768, N=1024, K=256]
  gemm_bt<0><<<dim3(8, 256), 256, 0, stream>>>(XBF, WIH0, BIAS0, XP, H_, I_);
  // fused decoupled 2-layer scan; final h2 lands in H2PP slot 1
  rnn_fused<<<dim3(256), 512, 0, stream>>>(WHH0, WIH1, WHH1, XP, BIAS1, H1, H2PP, BAR);
  // out = h2_last @ fcW^T + fcb
  fc_kernel<<<dim3(16, 4), 64, 0, stream>>>(H2PP + (size_t)B_*H_, FCW, fcb, (float*)d_out);
}

// Round 15
// 1959.303 us; speedup vs baseline: 3.4046x; 1.0696x over previous
//
#include <hip/hip_runtime.h>
#include <cstdint>
#include <cstddef>

// ---------- types ----------
typedef __attribute__((ext_vector_type(8))) short short8;   // 8 bf16 in 4 VGPRs
typedef __attribute__((ext_vector_type(4))) float f32x4;

#define B_ 64
#define T_ 512
#define I_ 256
#define H_ 1024
#define O_ 256

__device__ __forceinline__ unsigned short f32_to_bf16(float f) {
  unsigned int u = __float_as_uint(f);
  u += 0x7fffu + ((u >> 16) & 1u);           // RNE
  return (unsigned short)(u >> 16);
}
__device__ __forceinline__ float bf16_to_f32(unsigned short h) {
  return __uint_as_float(((unsigned int)h) << 16);
}

__device__ __forceinline__ void gload_lds16(const void* g, void* l) {
  __builtin_amdgcn_global_load_lds((const __attribute__((address_space(1))) void*)g,
                                   (__attribute__((address_space(3))) void*)l, 16, 0, 0);
}

// MALL-write-through stores (bypass L1/L2 -> no cache maintenance ever needed)
__device__ __forceinline__ void store_short_sc(void* p, unsigned short v) {
  unsigned int vv = v;
  asm volatile("global_store_short %0, %1, off sc0 sc1" :: "v"(p), "v"(vv) : "memory");
}
__device__ __forceinline__ void store_int_sc(void* p, int v) {
  asm volatile("global_store_dword %0, %1, off sc0 sc1" :: "v"(p), "v"(v) : "memory");
}
// MALL-coherent 16B load (inline asm: caller MUST s_waitcnt vmcnt before use!)
__device__ __forceinline__ short8 load16_sc(const void* p) {
  short8 r;
  asm volatile("global_load_dwordx4 %0, %1, off sc0 sc1" : "=v"(r) : "v"(p) : "memory");
  return r;
}
// pinned (non-rematerializable) 16B load: executes exactly once (cached path ok)
__device__ __forceinline__ short8 pinned_load16(const void* p) {
  short8 r;
  asm volatile("global_load_dwordx4 %0, %1, off" : "=v"(r) : "v"(p));
  return r;
}

// ---------- conversion kernels ----------
__global__ void cvt_f32_bf16(const float4* __restrict__ s, ushort4* __restrict__ d, int n4) {
  int i = blockIdx.x * blockDim.x + threadIdx.x;
  if (i >= n4) return;
  float4 v = s[i];
  ushort4 o;
  o.x = f32_to_bf16(v.x); o.y = f32_to_bf16(v.y);
  o.z = f32_to_bf16(v.z); o.w = f32_to_bf16(v.w);
  d[i] = o;
}

__global__ void bias_sum(const float* __restrict__ a, const float* __restrict__ b,
                         float* __restrict__ o, int n) {
  int i = blockIdx.x * blockDim.x + threadIdx.x;
  if (i < n) o[i] = a[i] + b[i];
}

// ---------- GEMM: C[M,N] = A[M,K] @ Bm[N,K]^T + bias, 128x128 tile (m97 structure) ----------
template<int OUT_F32>
__global__ __launch_bounds__(256) void gemm_bt(
    const unsigned short* __restrict__ A, const unsigned short* __restrict__ Bm,
    const float* __restrict__ bias, void* __restrict__ Cout, int N_, int K_)
{
  __shared__ unsigned short As[128*32];
  __shared__ unsigned short Bs[128*32];
  const int tid = threadIdx.x;
  const int l = tid & 63, w = tid >> 6;
  const int row0 = blockIdx.y * 128, col0 = blockIdx.x * 128;
  const int wr = w >> 1, wc = w & 1;          // 2x2 waves, each 64x64
  const int lrow = l & 15, lk8 = (l >> 4) * 8;

  f32x4 acc[4][4] = {};

  const int nkb = K_ >> 5;
  for (int kb = 0; kb < nkb; ++kb) {
    #pragma unroll
    for (int c = 0; c < 2; ++c) {
      const int off = w*2048 + c*1024 + l*16;   // byte offset within 8KB tile
      const int row = off >> 6, colb = off & 63;
      gload_lds16((const char*)A  + ((size_t)(row0+row)*K_ + kb*32)*2 + colb,
                  (char*)As + w*2048 + c*1024);
      gload_lds16((const char*)Bm + ((size_t)(col0+row)*K_ + kb*32)*2 + colb,
                  (char*)Bs + w*2048 + c*1024);
    }
    __syncthreads();
    short8 af[4], bfr[4];
    #pragma unroll
    for (int m=0;m<4;++m) af[m]  = *(const short8*)&As[(wr*64 + m*16 + lrow)*32 + lk8];
    #pragma unroll
    for (int n=0;n<4;++n) bfr[n] = *(const short8*)&Bs[(wc*64 + n*16 + lrow)*32 + lk8];
    #pragma unroll
    for (int m=0;m<4;++m)
      #pragma unroll
      for (int n=0;n<4;++n)
        acc[m][n] = __builtin_amdgcn_mfma_f32_16x16x32_bf16(af[m], bfr[n], acc[m][n], 0,0,0);
    __syncthreads();
  }

  #pragma unroll
  for (int n=0;n<4;++n) {
    const int col = col0 + wc*64 + n*16 + lrow;
    const float bv = bias[col];
    #pragma unroll
    for (int m=0;m<4;++m) {
      const int rowb = row0 + wr*64 + m*16 + (l>>4)*4;
      #pragma unroll
      for (int r=0;r<4;++r) {
        const float v = acc[m][n][r] + bv;
        if (OUT_F32) ((float*)Cout)[(size_t)(rowb+r)*N_ + col] = v;
        else ((unsigned short*)Cout)[(size_t)(rowb+r)*N_ + col] = f32_to_bf16(v);
      }
    }
  }
}

// ---------- fused decoupled 2-layer RNN ----------
// 256 wgs x 512 threads, LB(512,2) — 1 wg/CU on all 256 CUs.
// ENVELOPE LAW (r6/7/8/10/14 post-mortems): 512-thr wg => 2 waves/SIMD =>
// <=256 regs/wave TOTAL; never asm-pin more than 128 regs/wave.
// wgs 0-127: LAYER 0 = r5's proven scan (fan-in 8, ~2.4us/step), publish-all-t.
// wgs 128-255: LAYER 1 wave-role split (waves 0-3 pin Wih1 -> aI; waves 4-7
//   pin Whh1 -> aH; LDS comb handoff). Fan-in 16 (structurally forced).
// r15 delta (L1 staging only): flags0 poll + h1_{s+1} load issue moved BEFORE
// the h2-store drain — their MALL RT rides the drain (shared vmcnt(0)),
// removing ~1 serial RT per step. Ordering semantics identical to r13.
#define L0_STEP(tcur, XREG)                                                          \
  {                                                                                  \
    const int t = (tcur);                                                            \
    f32x4 acc0 = {}, acc1 = {}, acc2 = {}, acc3 = {};                                \
    if (t > 0) {                                                                     \
      _Pragma("unroll")                                                              \
      for (int kk = 0; kk < 32; kk += 4) {                                           \
        short8 a0 = *(const short8*)&lds_h1[arow][(kk+0)*32 + lk8];                  \
        short8 a1 = *(const short8*)&lds_h1[arow][(kk+1)*32 + lk8];                  \
        short8 a2 = *(const short8*)&lds_h1[arow][(kk+2)*32 + lk8];                  \
        short8 a3 = *(const short8*)&lds_h1[arow][(kk+3)*32 + lk8];                  \
        acc0 = __builtin_amdgcn_mfma_f32_16x16x32_bf16(a0, breg[kk+0], acc0, 0,0,0); \
        acc1 = __builtin_amdgcn_mfma_f32_16x16x32_bf16(a1, breg[kk+1], acc1, 0,0,0); \
        acc2 = __builtin_amdgcn_mfma_f32_16x16x32_bf16(a2, breg[kk+2], acc2, 0,0,0); \
        acc3 = __builtin_amdgcn_mfma_f32_16x16x32_bf16(a3, breg[kk+3], acc3, 0,0,0); \
      }                                                                              \
    }                                                                                \
    if (l < 16) {                                                                    \
      _Pragma("unroll")                                                              \
      for (int r = 0; r < 4; ++r) {                                                  \
        const int s = sg*4 + r;                                                      \
        float v = acc0[r] + acc1[r] + acc2[r] + acc3[r]                              \
                + bf16_to_f32((unsigned short)XREG[r]);                              \
        v = fmaxf(v, 0.f);                                                           \
        store_short_sc(h1buf + ((size_t)s*T_ + t)*H_ + col, f32_to_bf16(v));         \
      }                                                                              \
    }                                                                                \
    asm volatile("s_waitcnt vmcnt(0)" ::: "memory");     /* h1 stores at MALL */     \
    __syncthreads();                                     /* all 8 waves drained */   \
    if (tid == 0) store_int_sc(&flags0g[rgO], t+1);      /* publish ALL t */         \
    if (t < T_-1) {                                                                  \
      { int fv;                                                                      \
        do { fv = __hip_atomic_load(flags0g + (l & 7), __ATOMIC_RELAXED,             \
                                    __HIP_MEMORY_SCOPE_AGENT);                       \
        } while (!__all(fv >= t+1)); }                                               \
      const unsigned short* hrow = h1buf + ((size_t)(sg*4 + (w>>1))*T_ + t)*H_;      \
      const int tn = (t+2 < T_) ? (t+2) : (T_-1);                                    \
      const unsigned short* xpp = xp + ((size_t)(sg*4)*T_ + tn)*H_ + col;            \
      short8 sv = load16_sc(hrow + (w&1)*512 + l*8);     /* 1 outstanding */         \
      _Pragma("unroll")                                                              \
      for (int r = 0; r < 4; ++r)                        /* +4 outstanding */        \
        asm volatile("global_load_ushort %0, %1, off"                               \
                     : "=v"(XREG[r]) : "v"(xpp + (size_t)r*T_*H_) : "memory");       \
      asm volatile("s_waitcnt vmcnt(4)" ::: "memory");   /* wait stage load only */  \
      *(short8*)&lds_h1[w>>1][(w&1)*512 + l*8] = sv;                                 \
      __syncthreads();                                   /* LDS visible for t+1 */   \
    }                                                                                \
  }

__global__ __launch_bounds__(512, 2) void rnn_fused(
    const unsigned short* __restrict__ whh0,
    const unsigned short* __restrict__ wih1,
    const unsigned short* __restrict__ whh1,
    const unsigned short* __restrict__ xp,     // xp0 = x@Wih0^T + b  [B][T][H]
    const float* __restrict__ bias1,           // bih1 + bhh1
    unsigned short* __restrict__ h1buf,        // H1 [B][T][H] (full, no overwrite)
    unsigned short* __restrict__ h2pp,         // [2][B][H]; final h2 in slot 1
    int* __restrict__ bar)
{
  // 35,328 B static LDS (stay < 64KB — r10 lesson)
  __shared__ unsigned short lds_h1[8][1040];   // L0 uses rows 0..3 only
  __shared__ unsigned short lds_h2[8][1040];
  __shared__ float comb[4][8][16];             // L1 aH handoff

  const int wg = blockIdx.x;            // 0..255
  const int tid = threadIdx.x;          // 0..511
  const int l = tid & 63;
  const int w = tid >> 6;               // 0..7
  const int lrow = l & 15;
  const int lk8 = (l >> 4) * 8;

  if (wg < 128) {
    // ================= LAYER 0 (r5 verbatim, publish-all-t) =================
    const int sg = wg & 15;             // 4 samples
    const int rgO = wg >> 4;            // 0..7 (128 cols)
    const int col = rgO*128 + w*16 + lrow;
    const int arow = lrow & 3;
    int* flags0g = bar + sg*16;

    short8 breg[32];
    #pragma unroll
    for (int kk=0; kk<32; ++kk)
      breg[kk] = pinned_load16(&whh0[(size_t)col*H_ + kk*32 + lk8]);

    unsigned int xa[4], xb[4];
    #pragma unroll
    for (int r=0; r<4; ++r) {
      asm volatile("global_load_ushort %0, %1, off" : "=v"(xa[r])
        : "v"(xp + ((size_t)(sg*4+r)*T_ + 0)*H_ + col) : "memory");
      asm volatile("global_load_ushort %0, %1, off" : "=v"(xb[r])
        : "v"(xp + ((size_t)(sg*4+r)*T_ + 1)*H_ + col) : "memory");
    }
    asm volatile("s_waitcnt vmcnt(0)" ::: "memory");
    __builtin_amdgcn_sched_barrier(0);

    for (int t2 = 0; t2 < T_; t2 += 2) {
      L0_STEP(t2,   xa);
      L0_STEP(t2+1, xb);
    }
  } else {
    // ================= LAYER 1 (wave-role split, self-paced) =================
    const int lw = wg - 128;
    const int sg1 = lw >> 4;            // 0..7 (8 samples)
    const int rgO1 = lw & 15;           // 0..15 (64 cols)
    const int q = w & 3;                // col quad within wg
    const bool isI = (w < 4);           // waves 0-3: Wih1; 4-7: Whh1
    const int col = rgO1*64 + q*16 + lrow;
    const int arow = lrow & 7;          // 8 samples dup to 16 rows
    int* flags1g = bar + 1024 + sg1*16;
    const int fi0 = (2*sg1 + ((l>>3)&1))*16 + (l&7);   // L0 flags for my samples

    const unsigned short* wsel = isI ? wih1 : whh1;
    short8 breg[32];
    #pragma unroll
    for (int kk=0; kk<32; ++kk)
      breg[kk] = pinned_load16(&wsel[(size_t)col*H_ + kk*32 + lk8]);
    asm volatile("s_waitcnt vmcnt(0)" ::: "memory");
    __builtin_amdgcn_sched_barrier(0);

    const float b1v = bias1[col];

    // prologue: wait h1_0, stage into lds_h1 (wave w -> sample row w)
    { int fv;
      do { fv = __hip_atomic_load(bar + fi0, __ATOMIC_RELAXED,
                                  __HIP_MEMORY_SCOPE_AGENT);
      } while (!__all(fv >= 1)); }
    {
      short8 s0 = load16_sc(h1buf + ((size_t)(sg1*8 + w)*T_ + 0)*H_ + l*8);
      short8 s1 = load16_sc(h1buf + ((size_t)(sg1*8 + w)*T_ + 0)*H_ + 512 + l*8);
      asm volatile("s_waitcnt vmcnt(0)" ::: "memory");
      *(short8*)&lds_h1[w][l*8]       = s0;
      *(short8*)&lds_h1[w][512 + l*8] = s1;
      __syncthreads();
    }

    for (int s = 0; s < T_; ++s) {
      f32x4 a0 = {}, a1 = {};
      if (isI) {
        #pragma unroll
        for (int kk = 0; kk < 32; kk += 2) {
          short8 x0 = *(const short8*)&lds_h1[arow][(kk+0)*32 + lk8];
          short8 x1 = *(const short8*)&lds_h1[arow][(kk+1)*32 + lk8];
          a0 = __builtin_amdgcn_mfma_f32_16x16x32_bf16(x0, breg[kk+0], a0, 0,0,0);
          a1 = __builtin_amdgcn_mfma_f32_16x16x32_bf16(x1, breg[kk+1], a1, 0,0,0);
        }
      } else {
        if (s > 0) {
          #pragma unroll
          for (int kk = 0; kk < 32; kk += 2) {
            short8 x0 = *(const short8*)&lds_h2[arow][(kk+0)*32 + lk8];
            short8 x1 = *(const short8*)&lds_h2[arow][(kk+1)*32 + lk8];
            a0 = __builtin_amdgcn_mfma_f32_16x16x32_bf16(x0, breg[kk+0], a0, 0,0,0);
            a1 = __builtin_amdgcn_mfma_f32_16x16x32_bf16(x1, breg[kk+1], a1, 0,0,0);
          }
        }
        if (l < 32) {
          #pragma unroll
          for (int r = 0; r < 4; ++r)
            comb[q][(l>>4)*4 + r][lrow] = a0[r] + a1[r];
        }
      }
      __syncthreads();                                   // comb visible
      if (isI && l < 32) {
        #pragma unroll
        for (int r = 0; r < 4; ++r) {
          const int smp = sg1*8 + (l>>4)*4 + r;
          float v = a0[r] + a1[r] + comb[q][(l>>4)*4 + r][lrow] + b1v;
          v = fmaxf(v, 0.f);
          store_short_sc(h2pp + ((size_t)((s&1)*B_ + smp))*H_ + col, f32_to_bf16(v));
        }
      }
      if (s < T_-1) {
        // ---- r15: flags0 poll + h1 issue BEFORE the drain (RT rides drain) ----
        // (1) flags0 poll (single load) — L0 leads; RT overlaps our h2 stores
        { int v0;
          do { v0 = __hip_atomic_load(bar + fi0, __ATOMIC_RELAXED,
                                      __HIP_MEMORY_SCOPE_AGENT);
          } while (!__all(v0 >= s+2)); }
        // (2) issue h1_{s+1} stage loads — drain together with the h2 stores
        short8 t0 = load16_sc(h1buf + ((size_t)(sg1*8 + w)*T_ + (s+1))*H_ + l*8);
        short8 t1 = load16_sc(h1buf + ((size_t)(sg1*8 + w)*T_ + (s+1))*H_ + 512 + l*8);
        // (3) shared drain: h2 stores AND h1 loads at/back-from MALL
        asm volatile("s_waitcnt vmcnt(0)" ::: "memory");
        __syncthreads();                                  // all 8 waves drained
        if (tid == 0) store_int_sc(&flags1g[rgO1], s+1);
        // (4) flags1 poll (single load per iteration)
        { int v1;
          do { v1 = __hip_atomic_load(flags1g + (l & 15), __ATOMIC_RELAXED,
                                      __HIP_MEMORY_SCOPE_AGENT);
          } while (!__all(v1 >= s+1)); }
        // (5) h2 loads + drain + LDS + sync
        short8 t2 = load16_sc(h2pp + ((size_t)((s&1)*B_ + sg1*8 + w))*H_ + l*8);
        short8 t3 = load16_sc(h2pp + ((size_t)((s&1)*B_ + sg1*8 + w))*H_ + 512 + l*8);
        asm volatile("s_waitcnt vmcnt(0)" ::: "memory");
        *(short8*)&lds_h1[w][l*8]       = t0;
        *(short8*)&lds_h1[w][512 + l*8] = t1;
        *(short8*)&lds_h2[w][l*8]       = t2;
        *(short8*)&lds_h2[w][512 + l*8] = t3;
        __syncthreads();
      } else {
        // final step: drain h2_511 stores before kernel end (fc reads next)
        asm volatile("s_waitcnt vmcnt(0)" ::: "memory");
      }
    }
  }
}

// ---------- final FC: out[64,256] = h2 @ fcW^T + fcb (f32 out) ----------
__global__ __launch_bounds__(64) void fc_kernel(const unsigned short* __restrict__ h,
                                                const unsigned short* __restrict__ fw,
                                                const float* __restrict__ fb,
                                                float* __restrict__ out) {
  const int l = threadIdx.x;
  const int bx = blockIdx.x, by = blockIdx.y;   // bx: 16 col tiles, by: 4 row tiles
  const int lrow = l & 15, lk8 = (l>>4)*8;
  f32x4 acc = {};
  #pragma unroll
  for (int kk=0; kk<32; ++kk) {
    short8 a = *(const short8*)&h [(size_t)(by*16 + lrow)*H_ + kk*32 + lk8];
    short8 b = *(const short8*)&fw[(size_t)(bx*16 + lrow)*H_ + kk*32 + lk8];
    acc = __builtin_amdgcn_mfma_f32_16x16x32_bf16(a, b, acc, 0,0,0);
  }
  const int col = bx*16 + lrow;
  const float bv = fb[col];
  #pragma unroll
  for (int r=0;r<4;++r) {
    const int row = by*16 + (l>>4)*4 + r;
    out[row*O_ + col] = acc[r] + bv;
  }
}

// ---------- launch ----------
extern "C" void kernel_launch(void* const* d_in, const int* in_sizes, int n_in,
                              void* d_out, int out_size, void* d_ws, size_t ws_size,
                              hipStream_t stream) {
  const float* x    = (const float*)d_in[0];
  const float* wih0 = (const float*)d_in[1];
  const float* bih0 = (const float*)d_in[2];
  const float* whh0 = (const float*)d_in[3];
  const float* bhh0 = (const float*)d_in[4];
  const float* wih1 = (const float*)d_in[5];
  const float* bih1 = (const float*)d_in[6];
  const float* whh1 = (const float*)d_in[7];
  const float* bhh1 = (const float*)d_in[8];
  const float* fcw  = (const float*)d_in[9];
  const float* fcb  = (const float*)d_in[10];

  char* ws = (char*)d_ws;
  // workspace layout (bytes)
  unsigned short* XBF  = (unsigned short*)(ws + 0);          // 16,777,216  x bf16
  unsigned short* WIH0 = (unsigned short*)(ws + 16777216);   //    524,288
  unsigned short* WHH0 = (unsigned short*)(ws + 17301504);   //  2,097,152
  unsigned short* WIH1 = (unsigned short*)(ws + 19398656);   //  2,097,152
  unsigned short* WHH1 = (unsigned short*)(ws + 21495808);   //  2,097,152
  unsigned short* FCW  = (unsigned short*)(ws + 23592960);   //    524,288
  float*          BIAS0= (float*)(ws + 24117248);            //      4,096
  float*          BIAS1= (float*)(ws + 24121344);            //      4,096
  unsigned short* XP   = (unsigned short*)(ws + 24125440);   // 67,108,864  xp0 [B][T][H]
  unsigned short* H1   = (unsigned short*)(ws + 91234304);   // 67,108,864  h1 [B][T][H]
  unsigned short* H2PP = (unsigned short*)(ws + 158343168);  //    262,144  h2 ping-pong
  int*            BAR  = (int*)(ws + 158605312);             //      8,192  flag lines

  // flags0 at BAR[0..255], flags1 at BAR[1024..1151] — all re-zeroed in-graph
  hipMemsetAsync(BAR, 0, 8192, stream);

  // fp32 -> bf16 conversions
  cvt_f32_bf16<<<dim3(8192), 256, 0, stream>>>((const float4*)x,    (ushort4*)XBF,  2097152);
  cvt_f32_bf16<<<dim3(256),  256, 0, stream>>>((const float4*)wih0, (ushort4*)WIH0, 65536);
  cvt_f32_bf16<<<dim3(1024), 256, 0, stream>>>((const float4*)whh0, (ushort4*)WHH0, 262144);
  cvt_f32_bf16<<<dim3(1024), 256, 0, stream>>>((const float4*)wih1, (ushort4*)WIH1, 262144);
  cvt_f32_bf16<<<dim3(1024), 256, 0, stream>>>((const float4*)whh1, (ushort4*)WHH1, 262144);
  cvt_f32_bf16<<<dim3(256),  256, 0, stream>>>((const float4*)fcw,  (ushort4*)FCW,  65536);
  bias_sum<<<dim3(4), 256, 0, stream>>>(bih0, bhh0, BIAS0, H_);
  bias_sum<<<dim3(4), 256, 0, stream>>>(bih1, bhh1, BIAS1, H_);

  // xp0 = x @ Wih0^T + (bih0+bhh0)   [M=32768, N=1024, K=256]
  gemm_bt<0><<<dim3(8, 256), 256, 0, stream>>>(XBF, WIH0, BIAS0, XP, H_, I_);
  // fused decoupled 2-layer scan; final h2 lands in H2PP slot 1
  rnn_fused<<<dim3(256), 512, 0, stream>>>(WHH0, WIH1, WHH1, XP, BIAS1, H1, H2PP, BAR);
  // out = h2_last @ fcW^T + fcb
  fc_kernel<<<dim3(16, 4), 64, 0, stream>>>(H2PP + (size_t)B_*H_, FCW, fcb, (float*)d_out);
}